// Round 2
// baseline (8476.706 us; speedup 1.0000x reference)
//
#include <hip/hip_runtime.h>
#include <math.h>

#define B_ 2
#define L_ 4096
#define DM 1024
#define DI 2048
#define HD 64
#define NH 32
#define DS 128
#define CH 256
#define NC 16
#define DPROJ 4384   // 2*DI + 2*DS + NH
#define CONVD 2304   // DI + 2*DS

typedef unsigned short u16;
typedef unsigned int u32;

__device__ __forceinline__ float silu_(float x) { return x / (1.0f + __expf(-x)); }
__device__ __forceinline__ float us2f(u16 u) {
  union { u32 i; float f; } c; c.i = ((u32)u) << 16; return c.f;
}
__device__ __forceinline__ u16 f2us(float f) {
  union { float f; u32 i; } c; c.f = f;
  u32 i = c.i;
  return (u16)((i + 0x7FFFu + ((i >> 16) & 1u)) >> 16);  // round-nearest-even
}
__device__ __forceinline__ void unpack8(uint4 v, float* o) {
  o[0] = us2f(v.x & 0xffffu); o[1] = us2f(v.x >> 16);
  o[2] = us2f(v.y & 0xffffu); o[3] = us2f(v.y >> 16);
  o[4] = us2f(v.z & 0xffffu); o[5] = us2f(v.z >> 16);
  o[6] = us2f(v.w & 0xffffu); o[7] = us2f(v.w >> 16);
}

// ---- in-proj GEMM: zxbcdt = x @ W_in, epilogue splits z/xBC(bf16), dt(softplus fp32)
__global__ __launch_bounds__(256) void gemm_in_k(const float* __restrict__ A,
                                                 const float* __restrict__ Bm,
                                                 const float* __restrict__ dt_bias,
                                                 u16* __restrict__ zb,
                                                 u16* __restrict__ xraw,
                                                 float* __restrict__ dtp) {
  __shared__ float As[16][64];
  __shared__ float Bs[16][64];
  const int t = threadIdx.x;
  const int m0 = blockIdx.y * 64, n0 = blockIdx.x * 64;
  const int tr = t >> 4, tc = t & 15;
  float acc[4][4] = {};
  for (int k0 = 0; k0 < DM; k0 += 16) {
#pragma unroll
    for (int i = 0; i < 4; ++i) {
      int e = i * 256 + t; int m = e >> 4, k = e & 15;
      As[k][m] = A[(size_t)(m0 + m) * DM + (k0 + k)];
    }
#pragma unroll
    for (int i = 0; i < 4; ++i) {
      int e = i * 256 + t; int kk = e >> 6, n = e & 63;
      int col = n0 + n;
      Bs[kk][n] = (col < DPROJ) ? Bm[(size_t)(k0 + kk) * DPROJ + col] : 0.0f;
    }
    __syncthreads();
#pragma unroll
    for (int kk = 0; kk < 16; ++kk) {
      float4 av = *(const float4*)&As[kk][tr * 4];
      float4 bv = *(const float4*)&Bs[kk][tc * 4];
      float am[4] = {av.x, av.y, av.z, av.w};
      float bn[4] = {bv.x, bv.y, bv.z, bv.w};
#pragma unroll
      for (int i = 0; i < 4; ++i)
#pragma unroll
        for (int j = 0; j < 4; ++j) acc[i][j] += am[i] * bn[j];
    }
    __syncthreads();
  }
#pragma unroll
  for (int i = 0; i < 4; ++i) {
    int row = m0 + tr * 4 + i;
    int col0 = n0 + tc * 4;
    if (n0 < DI) {
      u32 lo = (u32)f2us(acc[i][0]) | ((u32)f2us(acc[i][1]) << 16);
      u32 hi = (u32)f2us(acc[i][2]) | ((u32)f2us(acc[i][3]) << 16);
      *(uint2*)&zb[(size_t)row * DI + col0] = make_uint2(lo, hi);
    } else if (n0 < DI + CONVD) {
      u32 lo = (u32)f2us(acc[i][0]) | ((u32)f2us(acc[i][1]) << 16);
      u32 hi = (u32)f2us(acc[i][2]) | ((u32)f2us(acc[i][3]) << 16);
      *(uint2*)&xraw[(size_t)row * CONVD + (col0 - DI)] = make_uint2(lo, hi);
    } else {
#pragma unroll
      for (int j = 0; j < 4; ++j) {
        int col = col0 + j;
        if (col < DPROJ) {
          int h = col - (DI + CONVD);
          float v = acc[i][j] + dt_bias[h];
          dtp[(size_t)row * NH + h] = (v > 20.0f) ? v : log1pf(__expf(v));
        }
      }
    }
  }
}

// ---- out-proj GEMM: out = u(bf16) @ W_out(fp32) -> fp32
__global__ __launch_bounds__(256) void gemm_out_k(const u16* __restrict__ A,
                                                  const float* __restrict__ Bm,
                                                  float* __restrict__ C) {
  __shared__ float As[16][64];
  __shared__ float Bs[16][64];
  const int t = threadIdx.x;
  const int m0 = blockIdx.y * 64, n0 = blockIdx.x * 64;
  const int tr = t >> 4, tc = t & 15;
  float acc[4][4] = {};
  for (int k0 = 0; k0 < DI; k0 += 16) {
#pragma unroll
    for (int i = 0; i < 4; ++i) {
      int e = i * 256 + t; int m = e >> 4, k = e & 15;
      As[k][m] = us2f(A[(size_t)(m0 + m) * DI + (k0 + k)]);
    }
#pragma unroll
    for (int i = 0; i < 4; ++i) {
      int e = i * 256 + t; int kk = e >> 6, n = e & 63;
      Bs[kk][n] = Bm[(size_t)(k0 + kk) * DM + (n0 + n)];
    }
    __syncthreads();
#pragma unroll
    for (int kk = 0; kk < 16; ++kk) {
      float4 av = *(const float4*)&As[kk][tr * 4];
      float4 bv = *(const float4*)&Bs[kk][tc * 4];
      float am[4] = {av.x, av.y, av.z, av.w};
      float bn[4] = {bv.x, bv.y, bv.z, bv.w};
#pragma unroll
      for (int i = 0; i < 4; ++i)
#pragma unroll
        for (int j = 0; j < 4; ++j) acc[i][j] += am[i] * bn[j];
    }
    __syncthreads();
  }
#pragma unroll
  for (int i = 0; i < 4; ++i) {
    int row = m0 + tr * 4 + i;
    int col = n0 + tc * 4;
    float4 v = make_float4(acc[i][0], acc[i][1], acc[i][2], acc[i][3]);
    *(float4*)&C[(size_t)row * DM + col] = v;
  }
}

// ---- causal depthwise conv(4) + SiLU, bf16 in/out
__global__ __launch_bounds__(256) void conv_silu_k(const u16* __restrict__ xraw,
                                                   const float* __restrict__ cw,
                                                   const float* __restrict__ cb,
                                                   u16* __restrict__ xbc) {
  int idx = blockIdx.x * 256 + threadIdx.x;  // B_*L_*CONVD
  int ch = idx % CONVD;
  int bl = idx / CONVD;
  int l = bl & (L_ - 1);
  const u16* src = xraw + (size_t)bl * CONVD + ch;
  float4 w = *(const float4*)&cw[ch * 4];
  float acc = cb[ch];
  if (l >= 3) acc += us2f(src[-3 * CONVD]) * w.x;
  if (l >= 2) acc += us2f(src[-2 * CONVD]) * w.y;
  if (l >= 1) acc += us2f(src[-CONVD]) * w.z;
  acc += us2f(src[0]) * w.w;
  xbc[(size_t)bl * CONVD + ch] = f2us(silu_(acc));
}

// ---- per-(b,h,c) within-chunk cumsum of dt*A  (layout [b][h][c][l])
__global__ void acs_k(const float* __restrict__ dtp, const float* __restrict__ A_log,
                      float* __restrict__ Acs) {
  int idx = blockIdx.x * blockDim.x + threadIdx.x;
  if (idx >= B_ * NH * NC) return;
  int h = (idx >> 4) & (NH - 1);
  int c = idx & (NC - 1);
  int b = idx >> 9;
  float Ah = -__expf(A_log[h]);
  float run = 0.0f;
  size_t base = ((size_t)b * L_ + c * CH) * NH + h;
  float* out = Acs + (size_t)idx * CH;
  for (int l = 0; l < CH; ++l) {
    run += dtp[base + (size_t)l * NH] * Ah;
    out[l] = run;
  }
}

// ---- chunk end-states: states[b,c,h,p,n] fp32
__global__ __launch_bounds__(256) void states_k(const u16* __restrict__ xbc,
                                                const float* __restrict__ dtp,
                                                const float* __restrict__ Acs,
                                                float* __restrict__ states) {
  __shared__ float Xs[64][64];
  __shared__ float Bsh[64][128];
  __shared__ float wdec[64];
  const int t = threadIdx.x;
  const int h = blockIdx.x & 31, c = (blockIdx.x >> 5) & 15, b = blockIdx.x >> 9;
  const int p = t >> 2, sub = t & 3;
  float4 acc[8];
#pragma unroll
  for (int j = 0; j < 8; ++j) acc[j] = make_float4(0.f, 0.f, 0.f, 0.f);
  const size_t acsb = (((size_t)b * NH + h) * NC + c) * CH;
  const float acs_last = Acs[acsb + (CH - 1)];
  for (int lt = 0; lt < 4; ++lt) {
    const int l0 = c * CH + lt * 64;
#pragma unroll
    for (int i = 0; i < 2; ++i) {
      int ci = i * 256 + t; int ll = ci >> 3, pk = ci & 7;
      size_t row = (size_t)b * L_ + l0 + ll;
      uint4 v = *(const uint4*)&xbc[row * CONVD + h * HD + pk * 8];
      float d = dtp[row * NH + h];
      float o[8]; unpack8(v, o);
#pragma unroll
      for (int q = 0; q < 8; ++q) Xs[ll][pk * 8 + q] = o[q] * d;
    }
#pragma unroll
    for (int i = 0; i < 4; ++i) {
      int ci = i * 256 + t; int ll = ci >> 4, ck = ci & 15;
      size_t row = (size_t)b * L_ + l0 + ll;
      uint4 v = *(const uint4*)&xbc[row * CONVD + DI + ck * 8];
      float o[8]; unpack8(v, o);
#pragma unroll
      for (int q = 0; q < 8; ++q) Bsh[ll][ck * 8 + q] = o[q];
    }
    if (t < 64) wdec[t] = __expf(acs_last - Acs[acsb + lt * 64 + t]);
    __syncthreads();
    for (int ll = 0; ll < 64; ++ll) {
      float xw = Xs[ll][p] * wdec[ll];
      const float4* brow = (const float4*)&Bsh[ll][0];
#pragma unroll
      for (int j = 0; j < 8; ++j) {
        float4 bv = brow[sub + 4 * j];
        acc[j].x += xw * bv.x; acc[j].y += xw * bv.y;
        acc[j].z += xw * bv.z; acc[j].w += xw * bv.w;
      }
    }
    __syncthreads();
  }
  size_t sb = ((((size_t)b * NC + c) * NH + h) * HD + p) * DS;
#pragma unroll
  for (int j = 0; j < 8; ++j) *(float4*)&states[sb + sub * 4 + 16 * j] = acc[j];
}

// ---- inter-chunk scan (in place: end-states -> init-states)
__global__ __launch_bounds__(256) void scan_k(float* __restrict__ states,
                                              const float* __restrict__ Acs) {
  const int t = threadIdx.x;
  const int b = blockIdx.x >> 5, h = blockIdx.x & 31;
  float run[32];
#pragma unroll
  for (int i = 0; i < 32; ++i) run[i] = 0.0f;
  for (int c = 0; c < NC; ++c) {
    float dAl = __expf(Acs[(((size_t)b * NH + h) * NC + c) * CH + (CH - 1)]);
    size_t base = (((size_t)b * NC + c) * NH + h) * (size_t)(HD * DS);
#pragma unroll
    for (int i = 0; i < 32; ++i) {
      size_t e = base + (size_t)i * 256 + t;
      float s = states[e];
      states[e] = run[i];
      run[i] = dAl * run[i] + s;
    }
  }
}

// ---- intra-chunk output + state-output + D skip; wave-local rows, shfl bridge
__global__ __launch_bounds__(256) void ssd_out_k(const u16* __restrict__ xbc,
                                                 const float* __restrict__ dtp,
                                                 const float* __restrict__ Acs,
                                                 const float* __restrict__ states,
                                                 const float* __restrict__ Dvec,
                                                 u16* __restrict__ y) {
  __shared__ u16 Cl[64][128];     // bf16 C rows (broadcast reads only)
  __shared__ u16 Bsh[64][130];    // bf16 B rows, +2 pad: per-lane-row scalar reads
  __shared__ float Xsh[64][64];   // x*dt fp32 (broadcast row, lane=col)
  __shared__ float Sst[64][33];   // state chunk fp32, +1 pad
  __shared__ float AcsL[64];
  __shared__ float AcsS[64];
  const int t = threadIdx.x;
  const int wv = t >> 6, lane = t & 63;
  const int lt = blockIdx.x & 3;
  const int h = (blockIdx.x >> 2) & 31;
  const int c = (blockIdx.x >> 7) & 15;
  const int b = blockIdx.x >> 11;
  const size_t acsb = (((size_t)b * NH + h) * NC + c) * CH;
  const size_t rowbase = (size_t)b * L_ + c * CH;
#pragma unroll
  for (int i = 0; i < 4; ++i) {
    int ci = i * 256 + t; int ll = ci >> 4, ck = ci & 15;
    size_t row = rowbase + lt * 64 + ll;
    uint4 v = *(const uint4*)&xbc[row * CONVD + DI + DS + ck * 8];
    *(uint4*)&Cl[ll][ck * 8] = v;
  }
  if (t < 64) AcsL[t] = Acs[acsb + lt * 64 + t];
  float acc[16];
#pragma unroll
  for (int i = 0; i < 16; ++i) acc[i] = 0.0f;

  for (int st = 0; st <= lt; ++st) {
#pragma unroll
    for (int i = 0; i < 4; ++i) {
      int ci = i * 256 + t; int ll = ci >> 4, ck = ci & 15;
      size_t row = rowbase + st * 64 + ll;
      uint4 v = *(const uint4*)&xbc[row * CONVD + DI + ck * 8];
      *(u32*)&Bsh[ll][ck * 8 + 0] = v.x;
      *(u32*)&Bsh[ll][ck * 8 + 2] = v.y;
      *(u32*)&Bsh[ll][ck * 8 + 4] = v.z;
      *(u32*)&Bsh[ll][ck * 8 + 6] = v.w;
    }
#pragma unroll
    for (int i = 0; i < 2; ++i) {
      int ci = i * 256 + t; int ll = ci >> 3, pk = ci & 7;
      size_t row = rowbase + st * 64 + ll;
      uint4 v = *(const uint4*)&xbc[row * CONVD + h * HD + pk * 8];
      float d = dtp[row * NH + h];
      float o[8]; unpack8(v, o);
#pragma unroll
      for (int q = 0; q < 8; ++q) Xsh[ll][pk * 8 + q] = o[q] * d;
    }
    if (t < 64) AcsS[t] = Acs[acsb + st * 64 + t];
    __syncthreads();
    // scores: lane `lane` computes S[wv*16+i][lane] over n=0..127
    float sacc[16];
#pragma unroll
    for (int i = 0; i < 16; ++i) sacc[i] = 0.0f;
#pragma unroll
    for (int ck = 0; ck < 16; ++ck) {
      float bb[8];
#pragma unroll
      for (int q = 0; q < 8; ++q) bb[q] = us2f(Bsh[lane][ck * 8 + q]);
#pragma unroll
      for (int i = 0; i < 16; ++i) {
        uint4 cv = *(const uint4*)&Cl[wv * 16 + i][ck * 8];
        float cc[8]; unpack8(cv, cc);
        sacc[i] += cc[0] * bb[0] + cc[1] * bb[1] + cc[2] * bb[2] + cc[3] * bb[3] +
                   cc[4] * bb[4] + cc[5] * bb[5] + cc[6] * bb[6] + cc[7] * bb[7];
      }
    }
    float aS = AcsS[lane];
#pragma unroll
    for (int i = 0; i < 16; ++i) {
      int lrow = wv * 16 + i;
      float wgt = ((st < lt) || (lane <= lrow)) ? __expf(AcsL[lrow] - aS) : 0.0f;
      sacc[i] *= wgt;
    }
    // accumulate: acc[i] (= Y[wv*16+i][p=lane]) += sum_s S[l][s]*X[s][lane]
    for (int s = 0; s < 64; ++s) {
      float xv = Xsh[s][lane];
#pragma unroll
      for (int i = 0; i < 16; ++i) acc[i] += __shfl(sacc[i], s) * xv;
    }
    __syncthreads();
  }
  // state-output term: Yo[l][p] = exp(AcsL[l]) * dot(C[l,:], state[p,:])
  const size_t sb = (((size_t)b * NC + c) * NH + h) * (size_t)(HD * DS);
  float yo[16];
#pragma unroll
  for (int i = 0; i < 16; ++i) yo[i] = 0.0f;
  for (int n0 = 0; n0 < DS; n0 += 32) {
#pragma unroll
    for (int i = 0; i < 2; ++i) {
      int ci = i * 256 + t;  // 0..511
      int p = ci >> 3, j4 = ci & 7;
      float4 v = *(const float4*)&states[sb + (size_t)p * DS + n0 + j4 * 4];
      Sst[p][j4 * 4 + 0] = v.x; Sst[p][j4 * 4 + 1] = v.y;
      Sst[p][j4 * 4 + 2] = v.z; Sst[p][j4 * 4 + 3] = v.w;
    }
    __syncthreads();
    float sp_[32];
#pragma unroll
    for (int q = 0; q < 32; ++q) sp_[q] = Sst[lane][q];
#pragma unroll
    for (int i = 0; i < 16; ++i) {
      float s8 = 0.0f;
#pragma unroll
      for (int c8 = 0; c8 < 4; ++c8) {
        uint4 cv = *(const uint4*)&Cl[wv * 16 + i][n0 + c8 * 8];
        float cc[8]; unpack8(cv, cc);
#pragma unroll
        for (int q = 0; q < 8; ++q) s8 += cc[q] * sp_[c8 * 8 + q];
      }
      yo[i] += s8;
    }
    __syncthreads();
  }
  const float Dh = Dvec[h];
#pragma unroll
  for (int i = 0; i < 16; ++i) {
    int lrow = wv * 16 + i;
    size_t row = rowbase + lt * 64 + lrow;
    float xs = us2f(xbc[row * CONVD + h * HD + lane]);
    float val = acc[i] + __expf(AcsL[lrow]) * yo[i] + Dh * xs;
    y[row * DI + h * HD + lane] = f2us(val);
  }
}

// ---- gated RMSNorm in place on y (bf16)
__global__ __launch_bounds__(256) void gnorm_k(const u16* __restrict__ zb,
                                               const float* __restrict__ nw,
                                               u16* __restrict__ y) {
  const int row = blockIdx.x, t = threadIdx.x;
  const u16* zr = zb + (size_t)row * DI;
  u16* yr = y + (size_t)row * DI;
  uint4 zv = *(const uint4*)&zr[t * 8];
  uint4 yv = *(const uint4*)&yr[t * 8];
  float uz[8], uy[8];
  unpack8(zv, uz); unpack8(yv, uy);
  float u[8], ssum = 0.0f;
#pragma unroll
  for (int j = 0; j < 8; ++j) { u[j] = uy[j] * silu_(uz[j]); ssum += u[j] * u[j]; }
#pragma unroll
  for (int off = 32; off >= 1; off >>= 1) ssum += __shfl_xor(ssum, off, 64);
  __shared__ float red[4];
  if ((t & 63) == 0) red[t >> 6] = ssum;
  __syncthreads();
  float sc = rsqrtf((red[0] + red[1] + red[2] + red[3]) * (1.0f / DI) + 1e-5f);
  float4 w0 = *(const float4*)&nw[t * 8];
  float4 w1 = *(const float4*)&nw[t * 8 + 4];
  float o0 = u[0] * sc * w0.x, o1 = u[1] * sc * w0.y, o2 = u[2] * sc * w0.z, o3 = u[3] * sc * w0.w;
  float o4 = u[4] * sc * w1.x, o5 = u[5] * sc * w1.y, o6 = u[6] * sc * w1.z, o7 = u[7] * sc * w1.w;
  uint4 ov;
  ov.x = (u32)f2us(o0) | ((u32)f2us(o1) << 16);
  ov.y = (u32)f2us(o2) | ((u32)f2us(o3) << 16);
  ov.z = (u32)f2us(o4) | ((u32)f2us(o5) << 16);
  ov.w = (u32)f2us(o6) | ((u32)f2us(o7) << 16);
  *(uint4*)&yr[t * 8] = ov;
}

extern "C" void kernel_launch(void* const* d_in, const int* in_sizes, int n_in,
                              void* d_out, int out_size, void* d_ws, size_t ws_size,
                              hipStream_t stream) {
  const float* x      = (const float*)d_in[0];
  const float* W_in   = (const float*)d_in[1];
  const float* conv_w = (const float*)d_in[2];
  const float* conv_b = (const float*)d_in[3];
  const float* dt_b   = (const float*)d_in[4];
  const float* A_log  = (const float*)d_in[5];
  const float* Dvec   = (const float*)d_in[6];
  const float* norm_w = (const float*)d_in[7];
  const float* W_out  = (const float*)d_in[8];
  float* out = (float*)d_out;

  // workspace layout (144.7 MB total)
  u16* zb       = (u16*)d_ws;                              // 33.55 MB
  u16* xbc      = zb + (size_t)B_ * L_ * DI;               // 37.75 MB
  float* dtp    = (float*)(xbc + (size_t)B_ * L_ * CONVD); // 1.05 MB
  float* Acs    = dtp + (size_t)B_ * L_ * NH;              // 1.05 MB
  float* states = Acs + (size_t)B_ * NH * L_;              // 33.55 MB
  u16* uni      = (u16*)(states + (size_t)B_ * NC * NH * HD * DS);  // 37.75 MB
  u16* xraw = uni;  // dead after conv
  u16* y    = uni;  // aliases xraw

  const int Mrows = B_ * L_;
  dim3 g1((DPROJ + 63) / 64, Mrows / 64);
  gemm_in_k<<<g1, 256, 0, stream>>>(x, W_in, dt_b, zb, xraw, dtp);
  conv_silu_k<<<(Mrows * CONVD) / 256, 256, 0, stream>>>(xraw, conv_w, conv_b, xbc);
  acs_k<<<4, 256, 0, stream>>>(dtp, A_log, Acs);
  states_k<<<B_ * NC * NH, 256, 0, stream>>>(xbc, dtp, Acs, states);
  scan_k<<<B_ * NH, 256, 0, stream>>>(states, Acs);
  ssd_out_k<<<B_ * NC * NH * 4, 256, 0, stream>>>(xbc, dtp, Acs, states, Dvec, y);
  gnorm_k<<<Mrows, 256, 0, stream>>>(zb, norm_w, y);
  dim3 g2(DM / 64, Mrows / 64);
  gemm_out_k<<<g2, 256, 0, stream>>>(y, W_out, out);
}

// Round 3
// 2163.955 us; speedup vs baseline: 3.9172x; 3.9172x over previous
//
#include <hip/hip_runtime.h>
#include <math.h>

#define B_ 2
#define L_ 4096
#define DM 1024
#define DI 2048
#define HD 64
#define NH 32
#define DS 128
#define CH 256
#define NC 16
#define DPROJ 4384   // 2*DI + 2*DS + NH
#define CONVD 2304   // DI + 2*DS

typedef unsigned short u16;
typedef unsigned int u32;
typedef __attribute__((ext_vector_type(8))) short bf16x8;
typedef __attribute__((ext_vector_type(4))) float f32x4;

__device__ __forceinline__ float silu_(float x) { return x / (1.0f + __expf(-x)); }
__device__ __forceinline__ float us2f(u16 u) {
  union { u32 i; float f; } c; c.i = ((u32)u) << 16; return c.f;
}
__device__ __forceinline__ u16 f2us(float f) {
  union { float f; u32 i; } c; c.f = f;
  u32 i = c.i;
  return (u16)((i + 0x7FFFu + ((i >> 16) & 1u)) >> 16);  // round-nearest-even
}
__device__ __forceinline__ void unpack8(uint4 v, float* o) {
  o[0] = us2f(v.x & 0xffffu); o[1] = us2f(v.x >> 16);
  o[2] = us2f(v.y & 0xffffu); o[3] = us2f(v.y >> 16);
  o[4] = us2f(v.z & 0xffffu); o[5] = us2f(v.z >> 16);
  o[6] = us2f(v.w & 0xffffu); o[7] = us2f(v.w >> 16);
}

// ---- in-proj GEMM: zxbcdt = x @ W_in, epilogue splits z/xBC(bf16), dt(softplus fp32)
__global__ __launch_bounds__(256) void gemm_in_k(const float* __restrict__ A,
                                                 const float* __restrict__ Bm,
                                                 const float* __restrict__ dt_bias,
                                                 u16* __restrict__ zb,
                                                 u16* __restrict__ xraw,
                                                 float* __restrict__ dtp) {
  __shared__ float As[16][64];
  __shared__ float Bs[16][64];
  const int t = threadIdx.x;
  const int m0 = blockIdx.y * 64, n0 = blockIdx.x * 64;
  const int tr = t >> 4, tc = t & 15;
  float acc[4][4] = {};
  for (int k0 = 0; k0 < DM; k0 += 16) {
#pragma unroll
    for (int i = 0; i < 4; ++i) {
      int e = i * 256 + t; int m = e >> 4, k = e & 15;
      As[k][m] = A[(size_t)(m0 + m) * DM + (k0 + k)];
    }
#pragma unroll
    for (int i = 0; i < 4; ++i) {
      int e = i * 256 + t; int kk = e >> 6, n = e & 63;
      int col = n0 + n;
      Bs[kk][n] = (col < DPROJ) ? Bm[(size_t)(k0 + kk) * DPROJ + col] : 0.0f;
    }
    __syncthreads();
#pragma unroll
    for (int kk = 0; kk < 16; ++kk) {
      float4 av = *(const float4*)&As[kk][tr * 4];
      float4 bv = *(const float4*)&Bs[kk][tc * 4];
      float am[4] = {av.x, av.y, av.z, av.w};
      float bn[4] = {bv.x, bv.y, bv.z, bv.w};
#pragma unroll
      for (int i = 0; i < 4; ++i)
#pragma unroll
        for (int j = 0; j < 4; ++j) acc[i][j] += am[i] * bn[j];
    }
    __syncthreads();
  }
#pragma unroll
  for (int i = 0; i < 4; ++i) {
    int row = m0 + tr * 4 + i;
    int col0 = n0 + tc * 4;
    if (n0 < DI) {
      u32 lo = (u32)f2us(acc[i][0]) | ((u32)f2us(acc[i][1]) << 16);
      u32 hi = (u32)f2us(acc[i][2]) | ((u32)f2us(acc[i][3]) << 16);
      *(uint2*)&zb[(size_t)row * DI + col0] = make_uint2(lo, hi);
    } else if (n0 < DI + CONVD) {
      u32 lo = (u32)f2us(acc[i][0]) | ((u32)f2us(acc[i][1]) << 16);
      u32 hi = (u32)f2us(acc[i][2]) | ((u32)f2us(acc[i][3]) << 16);
      *(uint2*)&xraw[(size_t)row * CONVD + (col0 - DI)] = make_uint2(lo, hi);
    } else {
#pragma unroll
      for (int j = 0; j < 4; ++j) {
        int col = col0 + j;
        if (col < DPROJ) {
          int h = col - (DI + CONVD);
          float v = acc[i][j] + dt_bias[h];
          dtp[(size_t)row * NH + h] = (v > 20.0f) ? v : log1pf(__expf(v));
        }
      }
    }
  }
}

// ---- out-proj GEMM: out = u(bf16) @ W_out(fp32) -> fp32
__global__ __launch_bounds__(256) void gemm_out_k(const u16* __restrict__ A,
                                                  const float* __restrict__ Bm,
                                                  float* __restrict__ C) {
  __shared__ float As[16][64];
  __shared__ float Bs[16][64];
  const int t = threadIdx.x;
  const int m0 = blockIdx.y * 64, n0 = blockIdx.x * 64;
  const int tr = t >> 4, tc = t & 15;
  float acc[4][4] = {};
  for (int k0 = 0; k0 < DI; k0 += 16) {
#pragma unroll
    for (int i = 0; i < 4; ++i) {
      int e = i * 256 + t; int m = e >> 4, k = e & 15;
      As[k][m] = us2f(A[(size_t)(m0 + m) * DI + (k0 + k)]);
    }
#pragma unroll
    for (int i = 0; i < 4; ++i) {
      int e = i * 256 + t; int kk = e >> 6, n = e & 63;
      Bs[kk][n] = Bm[(size_t)(k0 + kk) * DM + (n0 + n)];
    }
    __syncthreads();
#pragma unroll
    for (int kk = 0; kk < 16; ++kk) {
      float4 av = *(const float4*)&As[kk][tr * 4];
      float4 bv = *(const float4*)&Bs[kk][tc * 4];
      float am[4] = {av.x, av.y, av.z, av.w};
      float bn[4] = {bv.x, bv.y, bv.z, bv.w};
#pragma unroll
      for (int i = 0; i < 4; ++i)
#pragma unroll
        for (int j = 0; j < 4; ++j) acc[i][j] += am[i] * bn[j];
    }
    __syncthreads();
  }
#pragma unroll
  for (int i = 0; i < 4; ++i) {
    int row = m0 + tr * 4 + i;
    int col = n0 + tc * 4;
    float4 v = make_float4(acc[i][0], acc[i][1], acc[i][2], acc[i][3]);
    *(float4*)&C[(size_t)row * DM + col] = v;
  }
}

// ---- causal depthwise conv(4) + SiLU, bf16 in/out
__global__ __launch_bounds__(256) void conv_silu_k(const u16* __restrict__ xraw,
                                                   const float* __restrict__ cw,
                                                   const float* __restrict__ cb,
                                                   u16* __restrict__ xbc) {
  int idx = blockIdx.x * 256 + threadIdx.x;  // B_*L_*CONVD
  int ch = idx % CONVD;
  int bl = idx / CONVD;
  int l = bl & (L_ - 1);
  const u16* src = xraw + (size_t)bl * CONVD + ch;
  float4 w = *(const float4*)&cw[ch * 4];
  float acc = cb[ch];
  if (l >= 3) acc += us2f(src[-3 * CONVD]) * w.x;
  if (l >= 2) acc += us2f(src[-2 * CONVD]) * w.y;
  if (l >= 1) acc += us2f(src[-CONVD]) * w.z;
  acc += us2f(src[0]) * w.w;
  xbc[(size_t)bl * CONVD + ch] = f2us(silu_(acc));
}

// ---- per-(b,h,c) within-chunk cumsum of dt*A  (layout [b][h][c][l])
__global__ void acs_k(const float* __restrict__ dtp, const float* __restrict__ A_log,
                      float* __restrict__ Acs) {
  int idx = blockIdx.x * blockDim.x + threadIdx.x;
  if (idx >= B_ * NH * NC) return;
  int h = (idx >> 4) & (NH - 1);
  int c = idx & (NC - 1);
  int b = idx >> 9;
  float Ah = -__expf(A_log[h]);
  float run = 0.0f;
  size_t base = ((size_t)b * L_ + c * CH) * NH + h;
  float* out = Acs + (size_t)idx * CH;
  for (int l = 0; l < CH; ++l) {
    run += dtp[base + (size_t)l * NH] * Ah;
    out[l] = run;
  }
}

// ---- chunk end-states: states[b,c,h,p,n] fp32
__global__ __launch_bounds__(256) void states_k(const u16* __restrict__ xbc,
                                                const float* __restrict__ dtp,
                                                const float* __restrict__ Acs,
                                                float* __restrict__ states) {
  __shared__ float Xs[64][64];
  __shared__ float Bsh[64][128];
  __shared__ float wdec[64];
  const int t = threadIdx.x;
  const int h = blockIdx.x & 31, c = (blockIdx.x >> 5) & 15, b = blockIdx.x >> 9;
  const int p = t >> 2, sub = t & 3;
  float4 acc[8];
#pragma unroll
  for (int j = 0; j < 8; ++j) acc[j] = make_float4(0.f, 0.f, 0.f, 0.f);
  const size_t acsb = (((size_t)b * NH + h) * NC + c) * CH;
  const float acs_last = Acs[acsb + (CH - 1)];
  for (int lt = 0; lt < 4; ++lt) {
    const int l0 = c * CH + lt * 64;
#pragma unroll
    for (int i = 0; i < 2; ++i) {
      int ci = i * 256 + t; int ll = ci >> 3, pk = ci & 7;
      size_t row = (size_t)b * L_ + l0 + ll;
      uint4 v = *(const uint4*)&xbc[row * CONVD + h * HD + pk * 8];
      float d = dtp[row * NH + h];
      float o[8]; unpack8(v, o);
#pragma unroll
      for (int q = 0; q < 8; ++q) Xs[ll][pk * 8 + q] = o[q] * d;
    }
#pragma unroll
    for (int i = 0; i < 4; ++i) {
      int ci = i * 256 + t; int ll = ci >> 4, ck = ci & 15;
      size_t row = (size_t)b * L_ + l0 + ll;
      uint4 v = *(const uint4*)&xbc[row * CONVD + DI + ck * 8];
      float o[8]; unpack8(v, o);
#pragma unroll
      for (int q = 0; q < 8; ++q) Bsh[ll][ck * 8 + q] = o[q];
    }
    if (t < 64) wdec[t] = __expf(acs_last - Acs[acsb + lt * 64 + t]);
    __syncthreads();
    for (int ll = 0; ll < 64; ++ll) {
      float xw = Xs[ll][p] * wdec[ll];
      const float4* brow = (const float4*)&Bsh[ll][0];
#pragma unroll
      for (int j = 0; j < 8; ++j) {
        float4 bv = brow[sub + 4 * j];
        acc[j].x += xw * bv.x; acc[j].y += xw * bv.y;
        acc[j].z += xw * bv.z; acc[j].w += xw * bv.w;
      }
    }
    __syncthreads();
  }
  size_t sb = ((((size_t)b * NC + c) * NH + h) * HD + p) * DS;
#pragma unroll
  for (int j = 0; j < 8; ++j) *(float4*)&states[sb + sub * 4 + 16 * j] = acc[j];
}

// ---- inter-chunk scan (in place: end-states -> init-states)
__global__ __launch_bounds__(256) void scan_k(float* __restrict__ states,
                                              const float* __restrict__ Acs) {
  const int t = threadIdx.x;
  const int b = blockIdx.x >> 5, h = blockIdx.x & 31;
  float run[32];
#pragma unroll
  for (int i = 0; i < 32; ++i) run[i] = 0.0f;
  for (int c = 0; c < NC; ++c) {
    float dAl = __expf(Acs[(((size_t)b * NH + h) * NC + c) * CH + (CH - 1)]);
    size_t base = (((size_t)b * NC + c) * NH + h) * (size_t)(HD * DS);
#pragma unroll
    for (int i = 0; i < 32; ++i) {
      size_t e = base + (size_t)i * 256 + t;
      float s = states[e];
      states[e] = run[i];
      run[i] = dAl * run[i] + s;
    }
  }
}

// ---- intra-chunk + state-output via MFMA 16x16x32 bf16 ----------------------
// LDS pool (u16 units):
//   C tile   [64][128] swizzled      @ 0      (8192)
//   B tile   [64][128] swizzled      @ 8192   (8192)   } reused by Sst [64][136]
//   Xt       [64][72]  (X^T, pad 8)  @ 16384  (4608)   }  (8704 <= 12800)
//   Pl       4 waves x [16][72]      @ 20992  (4608)
#define C_OFF 0
#define B_OFF 8192
#define XT_OFF 16384
#define PL_OFF 20992
#define SST_OFF 8192
#define POOL_SZ 25600

__global__ __launch_bounds__(256) void ssd_out_k(const u16* __restrict__ xbc,
                                                 const float* __restrict__ dtp,
                                                 const float* __restrict__ Acs,
                                                 const float* __restrict__ states,
                                                 const float* __restrict__ Dvec,
                                                 u16* __restrict__ y) {
  __shared__ u16 pool[POOL_SZ];
  __shared__ float AcsL[64];
  __shared__ float AcsS[64];
  const int t = threadIdx.x;
  const int wv = t >> 6, lane = t & 63;
  const int lt = blockIdx.x & 3;
  const int h = (blockIdx.x >> 2) & 31;
  const int c = (blockIdx.x >> 7) & 15;
  const int b = blockIdx.x >> 11;
  const size_t acsb = (((size_t)b * NH + h) * NC + c) * CH;
  const size_t rowbase = (size_t)b * L_ + c * CH;

  const int fr = lane & 15;        // fragment row/col index
  const int oct = lane >> 4;       // k-octet index
  const int swz = (fr & 7) << 3;   // u16 XOR swizzle for C/B tiles

  // stage C tile (this lt's 64 rows x 128), swizzled
#pragma unroll
  for (int i = 0; i < 4; ++i) {
    int ci = i * 256 + t; int ll = ci >> 4, ck = ci & 15;
    size_t row = rowbase + lt * 64 + ll;
    uint4 v = *(const uint4*)&xbc[row * CONVD + DI + DS + ck * 8];
    *(uint4*)&pool[C_OFF + ll * 128 + ((ck * 8) ^ ((ll & 7) << 3))] = v;
  }
  if (t < 64) AcsL[t] = Acs[acsb + lt * 64 + t];

  f32x4 acc_y[4];
#pragma unroll
  for (int i = 0; i < 4; ++i) acc_y[i] = (f32x4){0.f, 0.f, 0.f, 0.f};

  for (int st = 0; st <= lt; ++st) {
    // stage B tile (swizzled)
#pragma unroll
    for (int i = 0; i < 4; ++i) {
      int ci = i * 256 + t; int ll = ci >> 4, ck = ci & 15;
      size_t row = rowbase + st * 64 + ll;
      uint4 v = *(const uint4*)&xbc[row * CONVD + DI + ck * 8];
      *(uint4*)&pool[B_OFF + ll * 128 + ((ck * 8) ^ ((ll & 7) << 3))] = v;
    }
    // stage Xt[p][s] = x[s][p]*dt[s] (bf16, transposed, pad 72)
#pragma unroll
    for (int i = 0; i < 2; ++i) {
      int ci = i * 256 + t; int s = ci >> 3, pk = ci & 7;
      size_t row = rowbase + st * 64 + s;
      uint4 v = *(const uint4*)&xbc[row * CONVD + h * HD + pk * 8];
      float d = dtp[row * NH + h];
      float o[8]; unpack8(v, o);
#pragma unroll
      for (int q = 0; q < 8; ++q) pool[XT_OFF + (pk * 8 + q) * 72 + s] = f2us(o[q] * d);
    }
    if (t < 64) AcsS[t] = Acs[acsb + st * 64 + t];
    __syncthreads();

    // scores S (16 l-rows x 64 s) per wave, then P -> Pl strip (bf16)
#pragma unroll
    for (int ss4 = 0; ss4 < 4; ++ss4) {
      f32x4 sacc = (f32x4){0.f, 0.f, 0.f, 0.f};
#pragma unroll
      for (int kk = 0; kk < 4; ++kk) {
        bf16x8 ca = *(const bf16x8*)&pool[C_OFF + (wv * 16 + fr) * 128 + ((kk * 32 + oct * 8) ^ swz)];
        bf16x8 bb = *(const bf16x8*)&pool[B_OFF + (ss4 * 16 + fr) * 128 + ((kk * 32 + oct * 8) ^ swz)];
        sacc = __builtin_amdgcn_mfma_f32_16x16x32_bf16(ca, bb, sacc, 0, 0, 0);
      }
      float aS = AcsS[ss4 * 16 + fr];
      int s_tile = ss4 * 16 + fr;   // s within 64-tile: col = lane&15
#pragma unroll
      for (int i = 0; i < 4; ++i) {
        int r = oct * 4 + i;                     // l within wave strip
        int l_tile = wv * 16 + r;                // l within 64-tile
        float aL = AcsL[l_tile];
        float wgt = ((st < lt) || (s_tile <= l_tile)) ? __expf(aL - aS) : 0.0f;
        pool[PL_OFF + wv * 1152 + r * 72 + s_tile] = f2us(sacc[i] * wgt);
      }
    }
    // Y += P(16x64) . X(64x64)  [A from Pl strip, B from Xt]
#pragma unroll
    for (int pp4 = 0; pp4 < 4; ++pp4) {
#pragma unroll
      for (int kk2 = 0; kk2 < 2; ++kk2) {
        bf16x8 pa = *(const bf16x8*)&pool[PL_OFF + wv * 1152 + fr * 72 + kk2 * 32 + oct * 8];
        bf16x8 xb = *(const bf16x8*)&pool[XT_OFF + (pp4 * 16 + fr) * 72 + kk2 * 32 + oct * 8];
        acc_y[pp4] = __builtin_amdgcn_mfma_f32_16x16x32_bf16(pa, xb, acc_y[pp4], 0, 0, 0);
      }
    }
    __syncthreads();
  }

  // stage init-state (fp32 -> bf16) into Sst [p][136]
  {
    size_t sb = (((size_t)b * NC + c) * NH + h) * (size_t)(HD * DS);
#pragma unroll
    for (int i = 0; i < 8; ++i) {
      int ci = i * 256 + t; int p = ci >> 5, nk = ci & 31;
      float4 v = *(const float4*)&states[sb + (size_t)p * DS + nk * 4];
      u32 lo = (u32)f2us(v.x) | ((u32)f2us(v.y) << 16);
      u32 hi = (u32)f2us(v.z) | ((u32)f2us(v.w) << 16);
      *(uint2*)&pool[SST_OFF + p * 136 + nk * 4] = make_uint2(lo, hi);
    }
  }
  __syncthreads();

  // Yo = C . state^T  (post-scaled by exp(AcsL[l]))
  f32x4 yo[4];
#pragma unroll
  for (int i = 0; i < 4; ++i) yo[i] = (f32x4){0.f, 0.f, 0.f, 0.f};
#pragma unroll
  for (int pp4 = 0; pp4 < 4; ++pp4) {
#pragma unroll
    for (int kk = 0; kk < 4; ++kk) {
      bf16x8 ca = *(const bf16x8*)&pool[C_OFF + (wv * 16 + fr) * 128 + ((kk * 32 + oct * 8) ^ swz)];
      bf16x8 sbf = *(const bf16x8*)&pool[SST_OFF + (pp4 * 16 + fr) * 136 + kk * 32 + oct * 8];
      yo[pp4] = __builtin_amdgcn_mfma_f32_16x16x32_bf16(ca, sbf, yo[pp4], 0, 0, 0);
    }
  }

  // write y = Yd + exp(AcsL)*Yo + D*xs
  const float Dh = Dvec[h];
#pragma unroll
  for (int i = 0; i < 4; ++i) {
    int l_tile = wv * 16 + oct * 4 + i;
    float eL = __expf(AcsL[l_tile]);
    size_t row = rowbase + lt * 64 + l_tile;
#pragma unroll
    for (int pp4 = 0; pp4 < 4; ++pp4) {
      int col = h * HD + pp4 * 16 + fr;
      float xs = us2f(xbc[row * CONVD + col]);
      float val = acc_y[pp4][i] + eL * yo[pp4][i] + Dh * xs;
      y[row * DI + col] = f2us(val);
    }
  }
}

// ---- gated RMSNorm in place on y (bf16)
__global__ __launch_bounds__(256) void gnorm_k(const u16* __restrict__ zb,
                                               const float* __restrict__ nw,
                                               u16* __restrict__ y) {
  const int row = blockIdx.x, t = threadIdx.x;
  const u16* zr = zb + (size_t)row * DI;
  u16* yr = y + (size_t)row * DI;
  uint4 zv = *(const uint4*)&zr[t * 8];
  uint4 yv = *(const uint4*)&yr[t * 8];
  float uz[8], uy[8];
  unpack8(zv, uz); unpack8(yv, uy);
  float u[8], ssum = 0.0f;
#pragma unroll
  for (int j = 0; j < 8; ++j) { u[j] = uy[j] * silu_(uz[j]); ssum += u[j] * u[j]; }
#pragma unroll
  for (int off = 32; off >= 1; off >>= 1) ssum += __shfl_xor(ssum, off, 64);
  __shared__ float red[4];
  if ((t & 63) == 0) red[t >> 6] = ssum;
  __syncthreads();
  float sc = rsqrtf((red[0] + red[1] + red[2] + red[3]) * (1.0f / DI) + 1e-5f);
  float4 w0 = *(const float4*)&nw[t * 8];
  float4 w1 = *(const float4*)&nw[t * 8 + 4];
  float o0 = u[0] * sc * w0.x, o1 = u[1] * sc * w0.y, o2 = u[2] * sc * w0.z, o3 = u[3] * sc * w0.w;
  float o4 = u[4] * sc * w1.x, o5 = u[5] * sc * w1.y, o6 = u[6] * sc * w1.z, o7 = u[7] * sc * w1.w;
  uint4 ov;
  ov.x = (u32)f2us(o0) | ((u32)f2us(o1) << 16);
  ov.y = (u32)f2us(o2) | ((u32)f2us(o3) << 16);
  ov.z = (u32)f2us(o4) | ((u32)f2us(o5) << 16);
  ov.w = (u32)f2us(o6) | ((u32)f2us(o7) << 16);
  *(uint4*)&yr[t * 8] = ov;
}

extern "C" void kernel_launch(void* const* d_in, const int* in_sizes, int n_in,
                              void* d_out, int out_size, void* d_ws, size_t ws_size,
                              hipStream_t stream) {
  const float* x      = (const float*)d_in[0];
  const float* W_in   = (const float*)d_in[1];
  const float* conv_w = (const float*)d_in[2];
  const float* conv_b = (const float*)d_in[3];
  const float* dt_b   = (const float*)d_in[4];
  const float* A_log  = (const float*)d_in[5];
  const float* Dvec   = (const float*)d_in[6];
  const float* norm_w = (const float*)d_in[7];
  const float* W_out  = (const float*)d_in[8];
  float* out = (float*)d_out;

  // workspace layout (144.7 MB total)
  u16* zb       = (u16*)d_ws;                              // 33.55 MB
  u16* xbc      = zb + (size_t)B_ * L_ * DI;               // 37.75 MB
  float* dtp    = (float*)(xbc + (size_t)B_ * L_ * CONVD); // 1.05 MB
  float* Acs    = dtp + (size_t)B_ * L_ * NH;              // 1.05 MB
  float* states = Acs + (size_t)B_ * NH * L_;              // 33.55 MB
  u16* uni      = (u16*)(states + (size_t)B_ * NC * NH * HD * DS);  // 37.75 MB
  u16* xraw = uni;  // dead after conv
  u16* y    = uni;  // aliases xraw

  const int Mrows = B_ * L_;
  dim3 g1((DPROJ + 63) / 64, Mrows / 64);
  gemm_in_k<<<g1, 256, 0, stream>>>(x, W_in, dt_b, zb, xraw, dtp);
  conv_silu_k<<<(Mrows * CONVD) / 256, 256, 0, stream>>>(xraw, conv_w, conv_b, xbc);
  acs_k<<<4, 256, 0, stream>>>(dtp, A_log, Acs);
  states_k<<<B_ * NC * NH, 256, 0, stream>>>(xbc, dtp, Acs, states);
  scan_k<<<B_ * NH, 256, 0, stream>>>(states, Acs);
  ssd_out_k<<<B_ * NC * NH * 4, 256, 0, stream>>>(xbc, dtp, Acs, states, Dvec, y);
  gnorm_k<<<Mrows, 256, 0, stream>>>(zb, norm_w, y);
  dim3 g2(DM / 64, Mrows / 64);
  gemm_out_k<<<g2, 256, 0, stream>>>(y, W_out, out);
}

// Round 4
// 846.872 us; speedup vs baseline: 10.0094x; 2.5552x over previous
//
#include <hip/hip_runtime.h>
#include <math.h>

#define B_ 2
#define L_ 4096
#define DM 1024
#define DI 2048
#define HD 64
#define NH 32
#define DS 128
#define CH 256
#define NC 16
#define DPROJ 4384   // 2*DI + 2*DS + NH
#define CONVD 2304   // DI + 2*DS
#define NGEMM 4352   // z + xBC columns (dt handled separately)

typedef unsigned short u16;
typedef unsigned int u32;
typedef __attribute__((ext_vector_type(8))) short bf16x8;
typedef __attribute__((ext_vector_type(4))) float f32x4;

__device__ __forceinline__ float silu_(float x) { return x / (1.0f + __expf(-x)); }
__device__ __forceinline__ float us2f(u16 u) {
  union { u32 i; float f; } c; c.i = ((u32)u) << 16; return c.f;
}
__device__ __forceinline__ u16 f2us(float f) {
  union { float f; u32 i; } c; c.f = f;
  u32 i = c.i;
  return (u16)((i + 0x7FFFu + ((i >> 16) & 1u)) >> 16);  // round-nearest-even
}
__device__ __forceinline__ void unpack8(uint4 v, float* o) {
  o[0] = us2f(v.x & 0xffffu); o[1] = us2f(v.x >> 16);
  o[2] = us2f(v.y & 0xffffu); o[3] = us2f(v.y >> 16);
  o[4] = us2f(v.z & 0xffffu); o[5] = us2f(v.z >> 16);
  o[6] = us2f(v.w & 0xffffu); o[7] = us2f(v.w >> 16);
}

// ---- elementwise fp32 -> bf16 ----------------------------------------------
__global__ __launch_bounds__(256) void cvt_bf16_k(const float* __restrict__ in,
                                                  u16* __restrict__ out, int n8) {
  int idx = blockIdx.x * 256 + threadIdx.x;
  if (idx >= n8) return;
  const float4 a = *(const float4*)&in[idx * 8];
  const float4 b = *(const float4*)&in[idx * 8 + 4];
  uint4 v;
  v.x = (u32)f2us(a.x) | ((u32)f2us(a.y) << 16);
  v.y = (u32)f2us(a.z) | ((u32)f2us(a.w) << 16);
  v.z = (u32)f2us(b.x) | ((u32)f2us(b.y) << 16);
  v.w = (u32)f2us(b.z) | ((u32)f2us(b.w) << 16);
  *(uint4*)&out[idx * 8] = v;
}

// ---- transpose + convert: Wt[n][k] = (bf16) W[k][n] -------------------------
__global__ __launch_bounds__(256) void cvt_t_k(const float* __restrict__ W,
                                               u16* __restrict__ Wt,
                                               int ldW, int ldT) {
  __shared__ float tile[64][65];
  const int t = threadIdx.x;
  const int n0 = blockIdx.x * 64, k0 = blockIdx.y * 64;
#pragma unroll
  for (int i = 0; i < 16; ++i) {
    int j = i * 256 + t;
    int kk = j >> 6, nn = j & 63;
    tile[kk][nn] = W[(size_t)(k0 + kk) * ldW + n0 + nn];
  }
  __syncthreads();
#pragma unroll
  for (int i = 0; i < 16; ++i) {
    int j = i * 256 + t;
    int nn = j >> 6, kk = j & 63;
    Wt[(size_t)(n0 + nn) * ldT + k0 + kk] = f2us(tile[kk][nn]);
  }
}

// ---- bf16 MFMA GEMM: D = A(MxK) . Bt(NxK)^T, 128x128 tile, BK=64 -----------
// EPI 0: split bf16 into zb / xraw.   EPI 1: fp32 out (N = DM).
template <int KDIM, int NTN, int EPI>
__global__ __launch_bounds__(256) void gemm_bf16_k(const u16* __restrict__ A,
                                                   const u16* __restrict__ Bt,
                                                   u16* __restrict__ zb,
                                                   u16* __restrict__ xraw,
                                                   float* __restrict__ outf,
                                                   int nwg) {
  __shared__ u16 Al[128 * 64];
  __shared__ u16 Bl[128 * 64];
  const int t = threadIdx.x;
  const int wv = t >> 6, lane = t & 63;
  const int fr = lane & 15, oct = lane >> 4;
  const int wr = wv >> 1, wc = wv & 1;
  // XCD-aware swizzle (nwg % 8 == 0 for both instantiations)
  const int q = nwg >> 3;
  const int wg = (blockIdx.x & 7) * q + (blockIdx.x >> 3);
  const int bm = wg / NTN, bn = wg % NTN;
  const int m0 = bm * 128, n0 = bn * 128;
  const int sr = t >> 3, sc = t & 7;   // staging: row-group, slot

  f32x4 acc[4][4];
#pragma unroll
  for (int mm = 0; mm < 4; ++mm)
#pragma unroll
    for (int nn = 0; nn < 4; ++nn) acc[mm][nn] = (f32x4){0.f, 0.f, 0.f, 0.f};

  for (int k0 = 0; k0 < KDIM; k0 += 64) {
    uint4 ra[4], rb[4];
#pragma unroll
    for (int i = 0; i < 4; ++i) {
      ra[i] = *(const uint4*)&A[(size_t)(m0 + i * 32 + sr) * KDIM + k0 + sc * 8];
      rb[i] = *(const uint4*)&Bt[(size_t)(n0 + i * 32 + sr) * KDIM + k0 + sc * 8];
    }
    if (k0) __syncthreads();
#pragma unroll
    for (int i = 0; i < 4; ++i) {
      int off = (i * 32 + sr) * 64 + ((sc ^ (sr & 7)) * 8);
      *(uint4*)&Al[off] = ra[i];
      *(uint4*)&Bl[off] = rb[i];
    }
    __syncthreads();
#pragma unroll
    for (int kk = 0; kk < 2; ++kk) {
      bf16x8 af[4], bfr[4];
#pragma unroll
      for (int mm = 0; mm < 4; ++mm)
        af[mm] = *(const bf16x8*)&Al[(wr * 64 + mm * 16 + fr) * 64 +
                                     (((kk * 4 + oct) ^ (fr & 7)) * 8)];
#pragma unroll
      for (int nn = 0; nn < 4; ++nn)
        bfr[nn] = *(const bf16x8*)&Bl[(wc * 64 + nn * 16 + fr) * 64 +
                                      (((kk * 4 + oct) ^ (fr & 7)) * 8)];
#pragma unroll
      for (int mm = 0; mm < 4; ++mm)
#pragma unroll
        for (int nn = 0; nn < 4; ++nn)
          acc[mm][nn] = __builtin_amdgcn_mfma_f32_16x16x32_bf16(af[mm], bfr[nn],
                                                                acc[mm][nn], 0, 0, 0);
    }
  }
  if (EPI == 0) {
    const bool isz = (n0 < DI);
#pragma unroll
    for (int mm = 0; mm < 4; ++mm)
#pragma unroll
      for (int i = 0; i < 4; ++i) {
        size_t row = m0 + wr * 64 + mm * 16 + oct * 4 + i;
#pragma unroll
        for (int nn = 0; nn < 4; ++nn) {
          int col = n0 + wc * 64 + nn * 16 + fr;
          u16 v = f2us(acc[mm][nn][i]);
          if (isz) zb[row * DI + col] = v;
          else xraw[row * CONVD + (col - DI)] = v;
        }
      }
  } else {
#pragma unroll
    for (int mm = 0; mm < 4; ++mm)
#pragma unroll
      for (int i = 0; i < 4; ++i) {
        size_t row = m0 + wr * 64 + mm * 16 + oct * 4 + i;
#pragma unroll
        for (int nn = 0; nn < 4; ++nn) {
          int col = n0 + wc * 64 + nn * 16 + fr;
          outf[row * DM + col] = acc[mm][nn][i];
        }
      }
  }
}

// ---- dt columns in exact fp32: dtp = softplus(x @ W_in[:,4352:] + bias) -----
__global__ __launch_bounds__(256) void dt_gemm_k(const float* __restrict__ x,
                                                 const float* __restrict__ W,
                                                 const float* __restrict__ dtb,
                                                 float* __restrict__ dtp) {
  __shared__ float xs[8 * 1024];  // 32 KB
  const int t = threadIdx.x;
  const int row0 = blockIdx.x * 8;
#pragma unroll
  for (int i = 0; i < 8; ++i) {
    int j4 = i * 256 + t;
    *(float4*)&xs[j4 * 4] = *(const float4*)&x[(size_t)row0 * DM + j4 * 4];
  }
  __syncthreads();
  const int r = t >> 5, h = t & 31;
  float a0 = 0.f, a1 = 0.f, a2 = 0.f, a3 = 0.f;
  const float* wcol = W + (DI + CONVD) + h;
  const float* xr = &xs[r * 1024];
  for (int k = 0; k < 1024; k += 4) {
    float4 xv = *(const float4*)&xr[k];
    a0 += xv.x * wcol[(size_t)(k + 0) * DPROJ];
    a1 += xv.y * wcol[(size_t)(k + 1) * DPROJ];
    a2 += xv.z * wcol[(size_t)(k + 2) * DPROJ];
    a3 += xv.w * wcol[(size_t)(k + 3) * DPROJ];
  }
  float v = (a0 + a1) + (a2 + a3) + dtb[h];
  dtp[(size_t)(row0 + r) * NH + h] = (v > 20.0f) ? v : log1pf(__expf(v));
}

// ---- causal depthwise conv(4) + SiLU, bf16 in/out
__global__ __launch_bounds__(256) void conv_silu_k(const u16* __restrict__ xraw,
                                                   const float* __restrict__ cw,
                                                   const float* __restrict__ cb,
                                                   u16* __restrict__ xbc) {
  int idx = blockIdx.x * 256 + threadIdx.x;  // B_*L_*CONVD
  int ch = idx % CONVD;
  int bl = idx / CONVD;
  int l = bl & (L_ - 1);
  const u16* src = xraw + (size_t)bl * CONVD + ch;
  float4 w = *(const float4*)&cw[ch * 4];
  float acc = cb[ch];
  if (l >= 3) acc += us2f(src[-3 * CONVD]) * w.x;
  if (l >= 2) acc += us2f(src[-2 * CONVD]) * w.y;
  if (l >= 1) acc += us2f(src[-CONVD]) * w.z;
  acc += us2f(src[0]) * w.w;
  xbc[(size_t)bl * CONVD + ch] = f2us(silu_(acc));
}

// ---- per-(b,h,c) within-chunk cumsum of dt*A  (layout [b][h][c][l])
__global__ void acs_k(const float* __restrict__ dtp, const float* __restrict__ A_log,
                      float* __restrict__ Acs) {
  int idx = blockIdx.x * blockDim.x + threadIdx.x;
  if (idx >= B_ * NH * NC) return;
  int h = (idx >> 4) & (NH - 1);
  int c = idx & (NC - 1);
  int b = idx >> 9;
  float Ah = -__expf(A_log[h]);
  float run = 0.0f;
  size_t base = ((size_t)b * L_ + c * CH) * NH + h;
  float* out = Acs + (size_t)idx * CH;
  for (int l = 0; l < CH; ++l) {
    run += dtp[base + (size_t)l * NH] * Ah;
    out[l] = run;
  }
}

// ---- chunk end-states: states[b,c,h,p,n] fp32
__global__ __launch_bounds__(256) void states_k(const u16* __restrict__ xbc,
                                                const float* __restrict__ dtp,
                                                const float* __restrict__ Acs,
                                                float* __restrict__ states) {
  __shared__ float Xs[64][64];
  __shared__ float Bsh[64][128];
  __shared__ float wdec[64];
  const int t = threadIdx.x;
  const int h = blockIdx.x & 31, c = (blockIdx.x >> 5) & 15, b = blockIdx.x >> 9;
  const int p = t >> 2, sub = t & 3;
  float4 acc[8];
#pragma unroll
  for (int j = 0; j < 8; ++j) acc[j] = make_float4(0.f, 0.f, 0.f, 0.f);
  const size_t acsb = (((size_t)b * NH + h) * NC + c) * CH;
  const float acs_last = Acs[acsb + (CH - 1)];
  for (int lt = 0; lt < 4; ++lt) {
    const int l0 = c * CH + lt * 64;
#pragma unroll
    for (int i = 0; i < 2; ++i) {
      int ci = i * 256 + t; int ll = ci >> 3, pk = ci & 7;
      size_t row = (size_t)b * L_ + l0 + ll;
      uint4 v = *(const uint4*)&xbc[row * CONVD + h * HD + pk * 8];
      float d = dtp[row * NH + h];
      float o[8]; unpack8(v, o);
#pragma unroll
      for (int q = 0; q < 8; ++q) Xs[ll][pk * 8 + q] = o[q] * d;
    }
#pragma unroll
    for (int i = 0; i < 4; ++i) {
      int ci = i * 256 + t; int ll = ci >> 4, ck = ci & 15;
      size_t row = (size_t)b * L_ + l0 + ll;
      uint4 v = *(const uint4*)&xbc[row * CONVD + DI + ck * 8];
      float o[8]; unpack8(v, o);
#pragma unroll
      for (int q = 0; q < 8; ++q) Bsh[ll][ck * 8 + q] = o[q];
    }
    if (t < 64) wdec[t] = __expf(acs_last - Acs[acsb + lt * 64 + t]);
    __syncthreads();
    for (int ll = 0; ll < 64; ++ll) {
      float xw = Xs[ll][p] * wdec[ll];
      const float4* brow = (const float4*)&Bsh[ll][0];
#pragma unroll
      for (int j = 0; j < 8; ++j) {
        float4 bv = brow[sub + 4 * j];
        acc[j].x += xw * bv.x; acc[j].y += xw * bv.y;
        acc[j].z += xw * bv.z; acc[j].w += xw * bv.w;
      }
    }
    __syncthreads();
  }
  size_t sb = ((((size_t)b * NC + c) * NH + h) * HD + p) * DS;
#pragma unroll
  for (int j = 0; j < 8; ++j) *(float4*)&states[sb + sub * 4 + 16 * j] = acc[j];
}

// ---- inter-chunk scan (in place: end-states -> init-states)
__global__ __launch_bounds__(256) void scan_k(float* __restrict__ states,
                                              const float* __restrict__ Acs) {
  const int t = threadIdx.x;
  const int b = blockIdx.x >> 5, h = blockIdx.x & 31;
  float run[32];
#pragma unroll
  for (int i = 0; i < 32; ++i) run[i] = 0.0f;
  for (int c = 0; c < NC; ++c) {
    float dAl = __expf(Acs[(((size_t)b * NH + h) * NC + c) * CH + (CH - 1)]);
    size_t base = (((size_t)b * NC + c) * NH + h) * (size_t)(HD * DS);
#pragma unroll
    for (int i = 0; i < 32; ++i) {
      size_t e = base + (size_t)i * 256 + t;
      float s = states[e];
      states[e] = run[i];
      run[i] = dAl * run[i] + s;
    }
  }
}

// ---- intra-chunk + state-output via MFMA 16x16x32 bf16 ----------------------
#define C_OFF 0
#define B_OFF 8192
#define XT_OFF 16384
#define PL_OFF 20992
#define SST_OFF 8192
#define POOL_SZ 25600

__global__ __launch_bounds__(256) void ssd_out_k(const u16* __restrict__ xbc,
                                                 const float* __restrict__ dtp,
                                                 const float* __restrict__ Acs,
                                                 const float* __restrict__ states,
                                                 const float* __restrict__ Dvec,
                                                 u16* __restrict__ y) {
  __shared__ u16 pool[POOL_SZ];
  __shared__ float AcsL[64];
  __shared__ float AcsS[64];
  const int t = threadIdx.x;
  const int wv = t >> 6, lane = t & 63;
  const int lt = blockIdx.x & 3;
  const int h = (blockIdx.x >> 2) & 31;
  const int c = (blockIdx.x >> 7) & 15;
  const int b = blockIdx.x >> 11;
  const size_t acsb = (((size_t)b * NH + h) * NC + c) * CH;
  const size_t rowbase = (size_t)b * L_ + c * CH;

  const int fr = lane & 15;
  const int oct = lane >> 4;
  const int swz = (fr & 7) << 3;

#pragma unroll
  for (int i = 0; i < 4; ++i) {
    int ci = i * 256 + t; int ll = ci >> 4, ck = ci & 15;
    size_t row = rowbase + lt * 64 + ll;
    uint4 v = *(const uint4*)&xbc[row * CONVD + DI + DS + ck * 8];
    *(uint4*)&pool[C_OFF + ll * 128 + ((ck * 8) ^ ((ll & 7) << 3))] = v;
  }
  if (t < 64) AcsL[t] = Acs[acsb + lt * 64 + t];

  f32x4 acc_y[4];
#pragma unroll
  for (int i = 0; i < 4; ++i) acc_y[i] = (f32x4){0.f, 0.f, 0.f, 0.f};

  for (int st = 0; st <= lt; ++st) {
#pragma unroll
    for (int i = 0; i < 4; ++i) {
      int ci = i * 256 + t; int ll = ci >> 4, ck = ci & 15;
      size_t row = rowbase + st * 64 + ll;
      uint4 v = *(const uint4*)&xbc[row * CONVD + DI + ck * 8];
      *(uint4*)&pool[B_OFF + ll * 128 + ((ck * 8) ^ ((ll & 7) << 3))] = v;
    }
#pragma unroll
    for (int i = 0; i < 2; ++i) {
      int ci = i * 256 + t; int s = ci >> 3, pk = ci & 7;
      size_t row = rowbase + st * 64 + s;
      uint4 v = *(const uint4*)&xbc[row * CONVD + h * HD + pk * 8];
      float d = dtp[row * NH + h];
      float o[8]; unpack8(v, o);
#pragma unroll
      for (int q = 0; q < 8; ++q) pool[XT_OFF + (pk * 8 + q) * 72 + s] = f2us(o[q] * d);
    }
    if (t < 64) AcsS[t] = Acs[acsb + st * 64 + t];
    __syncthreads();

#pragma unroll
    for (int ss4 = 0; ss4 < 4; ++ss4) {
      f32x4 sacc = (f32x4){0.f, 0.f, 0.f, 0.f};
#pragma unroll
      for (int kk = 0; kk < 4; ++kk) {
        bf16x8 ca = *(const bf16x8*)&pool[C_OFF + (wv * 16 + fr) * 128 + ((kk * 32 + oct * 8) ^ swz)];
        bf16x8 bb = *(const bf16x8*)&pool[B_OFF + (ss4 * 16 + fr) * 128 + ((kk * 32 + oct * 8) ^ swz)];
        sacc = __builtin_amdgcn_mfma_f32_16x16x32_bf16(ca, bb, sacc, 0, 0, 0);
      }
      float aS = AcsS[ss4 * 16 + fr];
      int s_tile = ss4 * 16 + fr;
#pragma unroll
      for (int i = 0; i < 4; ++i) {
        int r = oct * 4 + i;
        int l_tile = wv * 16 + r;
        float aL = AcsL[l_tile];
        float wgt = ((st < lt) || (s_tile <= l_tile)) ? __expf(aL - aS) : 0.0f;
        pool[PL_OFF + wv * 1152 + r * 72 + s_tile] = f2us(sacc[i] * wgt);
      }
    }
#pragma unroll
    for (int pp4 = 0; pp4 < 4; ++pp4) {
#pragma unroll
      for (int kk2 = 0; kk2 < 2; ++kk2) {
        bf16x8 pa = *(const bf16x8*)&pool[PL_OFF + wv * 1152 + fr * 72 + kk2 * 32 + oct * 8];
        bf16x8 xb = *(const bf16x8*)&pool[XT_OFF + (pp4 * 16 + fr) * 72 + kk2 * 32 + oct * 8];
        acc_y[pp4] = __builtin_amdgcn_mfma_f32_16x16x32_bf16(pa, xb, acc_y[pp4], 0, 0, 0);
      }
    }
    __syncthreads();
  }

  {
    size_t sb = (((size_t)b * NC + c) * NH + h) * (size_t)(HD * DS);
#pragma unroll
    for (int i = 0; i < 8; ++i) {
      int ci = i * 256 + t; int p = ci >> 5, nk = ci & 31;
      float4 v = *(const float4*)&states[sb + (size_t)p * DS + nk * 4];
      u32 lo = (u32)f2us(v.x) | ((u32)f2us(v.y) << 16);
      u32 hi = (u32)f2us(v.z) | ((u32)f2us(v.w) << 16);
      *(uint2*)&pool[SST_OFF + p * 136 + nk * 4] = make_uint2(lo, hi);
    }
  }
  __syncthreads();

  f32x4 yo[4];
#pragma unroll
  for (int i = 0; i < 4; ++i) yo[i] = (f32x4){0.f, 0.f, 0.f, 0.f};
#pragma unroll
  for (int pp4 = 0; pp4 < 4; ++pp4) {
#pragma unroll
    for (int kk = 0; kk < 4; ++kk) {
      bf16x8 ca = *(const bf16x8*)&pool[C_OFF + (wv * 16 + fr) * 128 + ((kk * 32 + oct * 8) ^ swz)];
      bf16x8 sbf = *(const bf16x8*)&pool[SST_OFF + (pp4 * 16 + fr) * 136 + kk * 32 + oct * 8];
      yo[pp4] = __builtin_amdgcn_mfma_f32_16x16x32_bf16(ca, sbf, yo[pp4], 0, 0, 0);
    }
  }

  const float Dh = Dvec[h];
#pragma unroll
  for (int i = 0; i < 4; ++i) {
    int l_tile = wv * 16 + oct * 4 + i;
    float eL = __expf(AcsL[l_tile]);
    size_t row = rowbase + lt * 64 + l_tile;
#pragma unroll
    for (int pp4 = 0; pp4 < 4; ++pp4) {
      int col = h * HD + pp4 * 16 + fr;
      float xs = us2f(xbc[row * CONVD + col]);
      float val = acc_y[pp4][i] + eL * yo[pp4][i] + Dh * xs;
      y[row * DI + col] = f2us(val);
    }
  }
}

// ---- gated RMSNorm in place on y (bf16)
__global__ __launch_bounds__(256) void gnorm_k(const u16* __restrict__ zb,
                                               const float* __restrict__ nw,
                                               u16* __restrict__ y) {
  const int row = blockIdx.x, t = threadIdx.x;
  const u16* zr = zb + (size_t)row * DI;
  u16* yr = y + (size_t)row * DI;
  uint4 zv = *(const uint4*)&zr[t * 8];
  uint4 yv = *(const uint4*)&yr[t * 8];
  float uz[8], uy[8];
  unpack8(zv, uz); unpack8(yv, uy);
  float u[8], ssum = 0.0f;
#pragma unroll
  for (int j = 0; j < 8; ++j) { u[j] = uy[j] * silu_(uz[j]); ssum += u[j] * u[j]; }
#pragma unroll
  for (int off = 32; off >= 1; off >>= 1) ssum += __shfl_xor(ssum, off, 64);
  __shared__ float red[4];
  if ((t & 63) == 0) red[t >> 6] = ssum;
  __syncthreads();
  float sc = rsqrtf((red[0] + red[1] + red[2] + red[3]) * (1.0f / DI) + 1e-5f);
  float4 w0 = *(const float4*)&nw[t * 8];
  float4 w1 = *(const float4*)&nw[t * 8 + 4];
  float o0 = u[0] * sc * w0.x, o1 = u[1] * sc * w0.y, o2 = u[2] * sc * w0.z, o3 = u[3] * sc * w0.w;
  float o4 = u[4] * sc * w1.x, o5 = u[5] * sc * w1.y, o6 = u[6] * sc * w1.z, o7 = u[7] * sc * w1.w;
  uint4 ov;
  ov.x = (u32)f2us(o0) | ((u32)f2us(o1) << 16);
  ov.y = (u32)f2us(o2) | ((u32)f2us(o3) << 16);
  ov.z = (u32)f2us(o4) | ((u32)f2us(o5) << 16);
  ov.w = (u32)f2us(o6) | ((u32)f2us(o7) << 16);
  *(uint4*)&yr[t * 8] = ov;
}

extern "C" void kernel_launch(void* const* d_in, const int* in_sizes, int n_in,
                              void* d_out, int out_size, void* d_ws, size_t ws_size,
                              hipStream_t stream) {
  const float* x      = (const float*)d_in[0];
  const float* W_in   = (const float*)d_in[1];
  const float* conv_w = (const float*)d_in[2];
  const float* conv_b = (const float*)d_in[3];
  const float* dt_b   = (const float*)d_in[4];
  const float* A_log  = (const float*)d_in[5];
  const float* Dvec   = (const float*)d_in[6];
  const float* norm_w = (const float*)d_in[7];
  const float* W_out  = (const float*)d_in[8];
  float* out = (float*)d_out;

  // workspace layout (144.7 MB total, unchanged)
  u16* zb       = (u16*)d_ws;                              // 33.55 MB
  u16* xbc      = zb + (size_t)B_ * L_ * DI;               // 37.75 MB
  float* dtp    = (float*)(xbc + (size_t)B_ * L_ * CONVD); // 1.05 MB
  float* Acs    = dtp + (size_t)B_ * L_ * NH;              // 1.05 MB
  float* states = Acs + (size_t)B_ * NH * L_;              // 33.55 MB
  u16* uni      = (u16*)(states + (size_t)B_ * NC * NH * HD * DS);  // 37.75 MB
  u16* xraw = uni;  // dead after conv
  u16* y    = uni;  // aliases xraw

  // bf16 operand buffers parked inside the (not-yet-live) states region
  u16* xb16   = (u16*)states;                      // 16.78 MB
  u16* wint   = xb16 + (size_t)B_ * L_ * DM;       //  8.91 MB  (<= 33.55 total)
  u16* woutt  = (u16*)states;                      //  4.19 MB  (after ssd_out_k)

  const int Mrows = B_ * L_;

  cvt_bf16_k<<<(Mrows * DM / 8 + 255) / 256, 256, 0, stream>>>(x, xb16, Mrows * DM / 8);
  cvt_t_k<<<dim3(NGEMM / 64, DM / 64), 256, 0, stream>>>(W_in, wint, DPROJ, DM);

  const int nwg_in = (Mrows / 128) * (NGEMM / 128);   // 64*34 = 2176
  gemm_bf16_k<DM, NGEMM / 128, 0><<<nwg_in, 256, 0, stream>>>(
      xb16, wint, zb, xraw, nullptr, nwg_in);
  dt_gemm_k<<<Mrows / 8, 256, 0, stream>>>(x, W_in, dt_b, dtp);

  conv_silu_k<<<(Mrows * CONVD) / 256, 256, 0, stream>>>(xraw, conv_w, conv_b, xbc);
  acs_k<<<4, 256, 0, stream>>>(dtp, A_log, Acs);
  states_k<<<B_ * NC * NH, 256, 0, stream>>>(xbc, dtp, Acs, states);
  scan_k<<<B_ * NH, 256, 0, stream>>>(states, Acs);
  ssd_out_k<<<B_ * NC * NH * 4, 256, 0, stream>>>(xbc, dtp, Acs, states, Dvec, y);
  gnorm_k<<<Mrows, 256, 0, stream>>>(zb, norm_w, y);

  cvt_t_k<<<dim3(DM / 64, DI / 64), 256, 0, stream>>>(W_out, woutt, DM, DI);
  const int nwg_out = (Mrows / 128) * (DM / 128);     // 64*8 = 512
  gemm_bf16_k<DI, DM / 128, 1><<<nwg_out, 256, 0, stream>>>(
      y, woutt, nullptr, nullptr, out, nwg_out);
}

// Round 5
// 513.225 us; speedup vs baseline: 16.5165x; 1.6501x over previous
//
#include <hip/hip_runtime.h>
#include <math.h>

#define B_ 2
#define L_ 4096
#define DM 1024
#define DI 2048
#define HD 64
#define NH 32
#define DS 128
#define CH 256
#define NC 16
#define DPROJ 4384   // 2*DI + 2*DS + NH
#define CONVD 2304   // DI + 2*DS
#define NGEMM 4352   // z + xBC columns (dt handled separately)

typedef unsigned short u16;
typedef unsigned int u32;
typedef __attribute__((ext_vector_type(8))) short bf16x8;
typedef __attribute__((ext_vector_type(4))) float f32x4;

__device__ __forceinline__ float silu_(float x) { return x / (1.0f + __expf(-x)); }
__device__ __forceinline__ float us2f(u16 u) {
  union { u32 i; float f; } c; c.i = ((u32)u) << 16; return c.f;
}
__device__ __forceinline__ u16 f2us(float f) {
  union { float f; u32 i; } c; c.f = f;
  u32 i = c.i;
  return (u16)((i + 0x7FFFu + ((i >> 16) & 1u)) >> 16);  // round-nearest-even
}
__device__ __forceinline__ void unpack8(uint4 v, float* o) {
  o[0] = us2f(v.x & 0xffffu); o[1] = us2f(v.x >> 16);
  o[2] = us2f(v.y & 0xffffu); o[3] = us2f(v.y >> 16);
  o[4] = us2f(v.z & 0xffffu); o[5] = us2f(v.z >> 16);
  o[6] = us2f(v.w & 0xffffu); o[7] = us2f(v.w >> 16);
}
__device__ __forceinline__ void gload16(const u16* g, u16* l) {
  __builtin_amdgcn_global_load_lds(
      (const __attribute__((address_space(1))) void*)g,
      (__attribute__((address_space(3))) void*)l, 16, 0, 0);
}

// ---- elementwise fp32 -> bf16 ----------------------------------------------
__global__ __launch_bounds__(256) void cvt_bf16_k(const float* __restrict__ in,
                                                  u16* __restrict__ out, int n8) {
  int idx = blockIdx.x * 256 + threadIdx.x;
  if (idx >= n8) return;
  const float4 a = *(const float4*)&in[idx * 8];
  const float4 b = *(const float4*)&in[idx * 8 + 4];
  uint4 v;
  v.x = (u32)f2us(a.x) | ((u32)f2us(a.y) << 16);
  v.y = (u32)f2us(a.z) | ((u32)f2us(a.w) << 16);
  v.z = (u32)f2us(b.x) | ((u32)f2us(b.y) << 16);
  v.w = (u32)f2us(b.z) | ((u32)f2us(b.w) << 16);
  *(uint4*)&out[idx * 8] = v;
}

// ---- transpose + convert: Wt[n][k] = (bf16) W[k][n] -------------------------
__global__ __launch_bounds__(256) void cvt_t_k(const float* __restrict__ W,
                                               u16* __restrict__ Wt,
                                               int ldW, int ldT) {
  __shared__ float tile[64][65];
  const int t = threadIdx.x;
  const int n0 = blockIdx.x * 64, k0 = blockIdx.y * 64;
#pragma unroll
  for (int i = 0; i < 16; ++i) {
    int j = i * 256 + t;
    int kk = j >> 6, nn = j & 63;
    tile[kk][nn] = W[(size_t)(k0 + kk) * ldW + n0 + nn];
  }
  __syncthreads();
#pragma unroll
  for (int i = 0; i < 16; ++i) {
    int j = i * 256 + t;
    int nn = j >> 6, kk = j & 63;
    Wt[(size_t)(n0 + nn) * ldT + k0 + kk] = f2us(tile[kk][nn]);
  }
}

// ---- bf16 MFMA GEMM: D = A(MxK) . Bt(NxK)^T, 128x128 tile, BK=64 -----------
// m97 structure: global_load_lds(16B) staging, single LDS buffer, 2 barriers/K.
// Global source pre-swizzled (XOR involution) so LDS stays linear (rule #21).
// Epilogue: LDS-staged 64-row half-tiles -> fully coalesced wide stores.
// EPI 0: split bf16 into zb / xraw.   EPI 1: fp32 out (N = DM).
template <int KDIM, int NTN, int EPI>
__global__ __launch_bounds__(256) void gemm_bf16_k(const u16* __restrict__ A,
                                                   const u16* __restrict__ Bt,
                                                   u16* __restrict__ zb,
                                                   u16* __restrict__ xraw,
                                                   float* __restrict__ outf,
                                                   int nwg) {
  __shared__ u16 pool[(EPI == 1) ? 17408 : 16384];  // 34KB (fp32 epi) / 32KB
  u16* Al = pool;          // [128][64] linear
  u16* Bl = pool + 8192;   // [128][64] linear
  const int t = threadIdx.x;
  const int wv = t >> 6, lane = t & 63;
  const int fr = lane & 15, oct = lane >> 4;
  const int wr = wv >> 1, wc = wv & 1;
  // XCD-aware swizzle (nwg % 8 == 0 for both instantiations)
  const int q = nwg >> 3;
  const int wg = (blockIdx.x & 7) * q + (blockIdx.x >> 3);
  const int bm = wg / NTN, bn = wg % NTN;
  const int m0 = bm * 128, n0 = bn * 128;

  // staging decomposition: lane -> (row lr, 16B slot ls); pre-swizzled source
  const int lr = lane >> 3, ls = lane & 7;
  const int gslot = (ls ^ lr) * 8;   // XOR involution: LDS[r][s] = G[r][s^(r&7)]

  f32x4 acc[4][4];
#pragma unroll
  for (int mm = 0; mm < 4; ++mm)
#pragma unroll
    for (int nn = 0; nn < 4; ++nn) acc[mm][nn] = (f32x4){0.f, 0.f, 0.f, 0.f};

  for (int k0 = 0; k0 < KDIM; k0 += 64) {
    if (k0) __syncthreads();  // previous compute done before LDS overwrite
#pragma unroll
    for (int i = 0; i < 4; ++i) {
      const int rowA = wv * 32 + i * 8;  // wave-uniform LDS base row
      gload16(&A[(size_t)(m0 + rowA + lr) * KDIM + k0 + gslot], &Al[rowA * 64]);
      gload16(&Bt[(size_t)(n0 + rowA + lr) * KDIM + k0 + gslot], &Bl[rowA * 64]);
    }
    __syncthreads();  // compiler drains vmcnt(0) at barrier
#pragma unroll
    for (int kk = 0; kk < 2; ++kk) {
      bf16x8 af[4], bfr[4];
#pragma unroll
      for (int mm = 0; mm < 4; ++mm)
        af[mm] = *(const bf16x8*)&Al[(wr * 64 + mm * 16 + fr) * 64 +
                                     (((kk * 4 + oct) ^ (fr & 7)) * 8)];
#pragma unroll
      for (int nn = 0; nn < 4; ++nn)
        bfr[nn] = *(const bf16x8*)&Bl[(wc * 64 + nn * 16 + fr) * 64 +
                                      (((kk * 4 + oct) ^ (fr & 7)) * 8)];
#pragma unroll
      for (int mm = 0; mm < 4; ++mm)
#pragma unroll
        for (int nn = 0; nn < 4; ++nn)
          acc[mm][nn] = __builtin_amdgcn_mfma_f32_16x16x32_bf16(af[mm], bfr[nn],
                                                                acc[mm][nn], 0, 0, 0);
    }
  }

  // -------- coalesced epilogue via LDS half-tiles (64 rows per pass) --------
  if (EPI == 0) {
    const bool isz = (n0 < DI);
#pragma unroll
    for (int P = 0; P < 2; ++P) {
      __syncthreads();
      u16* Oh = pool;  // [64][136]
      if (wr == P) {
#pragma unroll
        for (int mm = 0; mm < 4; ++mm)
#pragma unroll
          for (int i = 0; i < 4; ++i) {
            int rloc = mm * 16 + oct * 4 + i;
#pragma unroll
            for (int nn = 0; nn < 4; ++nn)
              Oh[rloc * 136 + wc * 64 + nn * 16 + fr] = f2us(acc[mm][nn][i]);
          }
      }
      __syncthreads();
#pragma unroll
      for (int p = 0; p < 4; ++p) {
        int e = p * 256 + t;
        int row = e >> 4, cs = (e & 15) * 8;
        uint4 v = *(const uint4*)&Oh[row * 136 + cs];
        size_t grow = m0 + P * 64 + row;
        int col = n0 + cs;
        if (isz) *(uint4*)&zb[grow * DI + col] = v;
        else     *(uint4*)&xraw[grow * CONVD + (col - DI)] = v;
      }
    }
  } else {
#pragma unroll
    for (int P = 0; P < 2; ++P) {
      __syncthreads();
      float* Of = (float*)pool;  // [64][132]
      if (wr == P) {
#pragma unroll
        for (int mm = 0; mm < 4; ++mm)
#pragma unroll
          for (int i = 0; i < 4; ++i) {
            int rloc = mm * 16 + oct * 4 + i;
#pragma unroll
            for (int nn = 0; nn < 4; ++nn)
              Of[rloc * 132 + wc * 64 + nn * 16 + fr] = acc[mm][nn][i];
          }
      }
      __syncthreads();
#pragma unroll
      for (int p = 0; p < 8; ++p) {
        int e = p * 256 + t;
        int row = e >> 5, c4 = (e & 31) * 4;
        float4 v = *(const float4*)&Of[row * 132 + c4];
        *(float4*)&outf[(size_t)(m0 + P * 64 + row) * DM + n0 + c4] = v;
      }
    }
  }
}

// ---- dt columns in exact fp32: dtp = softplus(x @ W_in[:,4352:] + bias) -----
__global__ __launch_bounds__(256) void dt_gemm_k(const float* __restrict__ x,
                                                 const float* __restrict__ W,
                                                 const float* __restrict__ dtb,
                                                 float* __restrict__ dtp) {
  __shared__ float xs[8 * 1024];  // 32 KB
  const int t = threadIdx.x;
  const int row0 = blockIdx.x * 8;
#pragma unroll
  for (int i = 0; i < 8; ++i) {
    int j4 = i * 256 + t;
    *(float4*)&xs[j4 * 4] = *(const float4*)&x[(size_t)row0 * DM + j4 * 4];
  }
  __syncthreads();
  const int r = t >> 5, h = t & 31;
  float a0 = 0.f, a1 = 0.f, a2 = 0.f, a3 = 0.f;
  const float* wcol = W + (DI + CONVD) + h;
  const float* xr = &xs[r * 1024];
  for (int k = 0; k < 1024; k += 4) {
    float4 xv = *(const float4*)&xr[k];
    a0 += xv.x * wcol[(size_t)(k + 0) * DPROJ];
    a1 += xv.y * wcol[(size_t)(k + 1) * DPROJ];
    a2 += xv.z * wcol[(size_t)(k + 2) * DPROJ];
    a3 += xv.w * wcol[(size_t)(k + 3) * DPROJ];
  }
  float v = (a0 + a1) + (a2 + a3) + dtb[h];
  dtp[(size_t)(row0 + r) * NH + h] = (v > 20.0f) ? v : log1pf(__expf(v));
}

// ---- causal depthwise conv(4) + SiLU, bf16 in/out
__global__ __launch_bounds__(256) void conv_silu_k(const u16* __restrict__ xraw,
                                                   const float* __restrict__ cw,
                                                   const float* __restrict__ cb,
                                                   u16* __restrict__ xbc) {
  int idx = blockIdx.x * 256 + threadIdx.x;  // B_*L_*CONVD
  int ch = idx % CONVD;
  int bl = idx / CONVD;
  int l = bl & (L_ - 1);
  const u16* src = xraw + (size_t)bl * CONVD + ch;
  float4 w = *(const float4*)&cw[ch * 4];
  float acc = cb[ch];
  if (l >= 3) acc += us2f(src[-3 * CONVD]) * w.x;
  if (l >= 2) acc += us2f(src[-2 * CONVD]) * w.y;
  if (l >= 1) acc += us2f(src[-CONVD]) * w.z;
  acc += us2f(src[0]) * w.w;
  xbc[(size_t)bl * CONVD + ch] = f2us(silu_(acc));
}

// ---- per-(b,h,c) within-chunk cumsum of dt*A  (layout [b][h][c][l])
__global__ void acs_k(const float* __restrict__ dtp, const float* __restrict__ A_log,
                      float* __restrict__ Acs) {
  int idx = blockIdx.x * blockDim.x + threadIdx.x;
  if (idx >= B_ * NH * NC) return;
  int h = (idx >> 4) & (NH - 1);
  int c = idx & (NC - 1);
  int b = idx >> 9;
  float Ah = -__expf(A_log[h]);
  float run = 0.0f;
  size_t base = ((size_t)b * L_ + c * CH) * NH + h;
  float* out = Acs + (size_t)idx * CH;
  for (int l = 0; l < CH; ++l) {
    run += dtp[base + (size_t)l * NH] * Ah;
    out[l] = run;
  }
}

// ---- chunk end-states: states[b,c,h,p,n] fp32
__global__ __launch_bounds__(256) void states_k(const u16* __restrict__ xbc,
                                                const float* __restrict__ dtp,
                                                const float* __restrict__ Acs,
                                                float* __restrict__ states) {
  __shared__ float Xs[64][64];
  __shared__ float Bsh[64][128];
  __shared__ float wdec[64];
  const int t = threadIdx.x;
  const int h = blockIdx.x & 31, c = (blockIdx.x >> 5) & 15, b = blockIdx.x >> 9;
  const int p = t >> 2, sub = t & 3;
  float4 acc[8];
#pragma unroll
  for (int j = 0; j < 8; ++j) acc[j] = make_float4(0.f, 0.f, 0.f, 0.f);
  const size_t acsb = (((size_t)b * NH + h) * NC + c) * CH;
  const float acs_last = Acs[acsb + (CH - 1)];
  for (int lt = 0; lt < 4; ++lt) {
    const int l0 = c * CH + lt * 64;
#pragma unroll
    for (int i = 0; i < 2; ++i) {
      int ci = i * 256 + t; int ll = ci >> 3, pk = ci & 7;
      size_t row = (size_t)b * L_ + l0 + ll;
      uint4 v = *(const uint4*)&xbc[row * CONVD + h * HD + pk * 8];
      float d = dtp[row * NH + h];
      float o[8]; unpack8(v, o);
#pragma unroll
      for (int q = 0; q < 8; ++q) Xs[ll][pk * 8 + q] = o[q] * d;
    }
#pragma unroll
    for (int i = 0; i < 4; ++i) {
      int ci = i * 256 + t; int ll = ci >> 4, ck = ci & 15;
      size_t row = (size_t)b * L_ + l0 + ll;
      uint4 v = *(const uint4*)&xbc[row * CONVD + DI + ck * 8];
      float o[8]; unpack8(v, o);
#pragma unroll
      for (int q = 0; q < 8; ++q) Bsh[ll][ck * 8 + q] = o[q];
    }
    if (t < 64) wdec[t] = __expf(acs_last - Acs[acsb + lt * 64 + t]);
    __syncthreads();
    for (int ll = 0; ll < 64; ++ll) {
      float xw = Xs[ll][p] * wdec[ll];
      const float4* brow = (const float4*)&Bsh[ll][0];
#pragma unroll
      for (int j = 0; j < 8; ++j) {
        float4 bv = brow[sub + 4 * j];
        acc[j].x += xw * bv.x; acc[j].y += xw * bv.y;
        acc[j].z += xw * bv.z; acc[j].w += xw * bv.w;
      }
    }
    __syncthreads();
  }
  size_t sb = ((((size_t)b * NC + c) * NH + h) * HD + p) * DS;
#pragma unroll
  for (int j = 0; j < 8; ++j) *(float4*)&states[sb + sub * 4 + 16 * j] = acc[j];
}

// ---- inter-chunk scan (in place: end-states -> init-states)
__global__ __launch_bounds__(256) void scan_k(float* __restrict__ states,
                                              const float* __restrict__ Acs) {
  const int t = threadIdx.x;
  const int b = blockIdx.x >> 5, h = blockIdx.x & 31;
  float run[32];
#pragma unroll
  for (int i = 0; i < 32; ++i) run[i] = 0.0f;
  for (int c = 0; c < NC; ++c) {
    float dAl = __expf(Acs[(((size_t)b * NH + h) * NC + c) * CH + (CH - 1)]);
    size_t base = (((size_t)b * NC + c) * NH + h) * (size_t)(HD * DS);
#pragma unroll
    for (int i = 0; i < 32; ++i) {
      size_t e = base + (size_t)i * 256 + t;
      float s = states[e];
      states[e] = run[i];
      run[i] = dAl * run[i] + s;
    }
  }
}

// ---- intra-chunk + state-output via MFMA 16x16x32 bf16 ----------------------
#define C_OFF 0
#define B_OFF 8192
#define XT_OFF 16384
#define PL_OFF 20992
#define SST_OFF 8192
#define POOL_SZ 25600

__global__ __launch_bounds__(256) void ssd_out_k(const u16* __restrict__ xbc,
                                                 const float* __restrict__ dtp,
                                                 const float* __restrict__ Acs,
                                                 const float* __restrict__ states,
                                                 const float* __restrict__ Dvec,
                                                 u16* __restrict__ y) {
  __shared__ u16 pool[POOL_SZ];
  __shared__ float AcsL[64];
  __shared__ float AcsS[64];
  const int t = threadIdx.x;
  const int wv = t >> 6, lane = t & 63;
  const int lt = blockIdx.x & 3;
  const int h = (blockIdx.x >> 2) & 31;
  const int c = (blockIdx.x >> 7) & 15;
  const int b = blockIdx.x >> 11;
  const size_t acsb = (((size_t)b * NH + h) * NC + c) * CH;
  const size_t rowbase = (size_t)b * L_ + c * CH;

  const int fr = lane & 15;
  const int oct = lane >> 4;
  const int swz = (fr & 7) << 3;

#pragma unroll
  for (int i = 0; i < 4; ++i) {
    int ci = i * 256 + t; int ll = ci >> 4, ck = ci & 15;
    size_t row = rowbase + lt * 64 + ll;
    uint4 v = *(const uint4*)&xbc[row * CONVD + DI + DS + ck * 8];
    *(uint4*)&pool[C_OFF + ll * 128 + ((ck * 8) ^ ((ll & 7) << 3))] = v;
  }
  if (t < 64) AcsL[t] = Acs[acsb + lt * 64 + t];

  f32x4 acc_y[4];
#pragma unroll
  for (int i = 0; i < 4; ++i) acc_y[i] = (f32x4){0.f, 0.f, 0.f, 0.f};

  for (int st = 0; st <= lt; ++st) {
#pragma unroll
    for (int i = 0; i < 4; ++i) {
      int ci = i * 256 + t; int ll = ci >> 4, ck = ci & 15;
      size_t row = rowbase + st * 64 + ll;
      uint4 v = *(const uint4*)&xbc[row * CONVD + DI + ck * 8];
      *(uint4*)&pool[B_OFF + ll * 128 + ((ck * 8) ^ ((ll & 7) << 3))] = v;
    }
#pragma unroll
    for (int i = 0; i < 2; ++i) {
      int ci = i * 256 + t; int s = ci >> 3, pk = ci & 7;
      size_t row = rowbase + st * 64 + s;
      uint4 v = *(const uint4*)&xbc[row * CONVD + h * HD + pk * 8];
      float d = dtp[row * NH + h];
      float o[8]; unpack8(v, o);
#pragma unroll
      for (int q = 0; q < 8; ++q) pool[XT_OFF + (pk * 8 + q) * 72 + s] = f2us(o[q] * d);
    }
    if (t < 64) AcsS[t] = Acs[acsb + st * 64 + t];
    __syncthreads();

#pragma unroll
    for (int ss4 = 0; ss4 < 4; ++ss4) {
      f32x4 sacc = (f32x4){0.f, 0.f, 0.f, 0.f};
#pragma unroll
      for (int kk = 0; kk < 4; ++kk) {
        bf16x8 ca = *(const bf16x8*)&pool[C_OFF + (wv * 16 + fr) * 128 + ((kk * 32 + oct * 8) ^ swz)];
        bf16x8 bb = *(const bf16x8*)&pool[B_OFF + (ss4 * 16 + fr) * 128 + ((kk * 32 + oct * 8) ^ swz)];
        sacc = __builtin_amdgcn_mfma_f32_16x16x32_bf16(ca, bb, sacc, 0, 0, 0);
      }
      float aS = AcsS[ss4 * 16 + fr];
      int s_tile = ss4 * 16 + fr;
#pragma unroll
      for (int i = 0; i < 4; ++i) {
        int r = oct * 4 + i;
        int l_tile = wv * 16 + r;
        float aL = AcsL[l_tile];
        float wgt = ((st < lt) || (s_tile <= l_tile)) ? __expf(aL - aS) : 0.0f;
        pool[PL_OFF + wv * 1152 + r * 72 + s_tile] = f2us(sacc[i] * wgt);
      }
    }
#pragma unroll
    for (int pp4 = 0; pp4 < 4; ++pp4) {
#pragma unroll
      for (int kk2 = 0; kk2 < 2; ++kk2) {
        bf16x8 pa = *(const bf16x8*)&pool[PL_OFF + wv * 1152 + fr * 72 + kk2 * 32 + oct * 8];
        bf16x8 xb = *(const bf16x8*)&pool[XT_OFF + (pp4 * 16 + fr) * 72 + kk2 * 32 + oct * 8];
        acc_y[pp4] = __builtin_amdgcn_mfma_f32_16x16x32_bf16(pa, xb, acc_y[pp4], 0, 0, 0);
      }
    }
    __syncthreads();
  }

  {
    size_t sb = (((size_t)b * NC + c) * NH + h) * (size_t)(HD * DS);
#pragma unroll
    for (int i = 0; i < 8; ++i) {
      int ci = i * 256 + t; int p = ci >> 5, nk = ci & 31;
      float4 v = *(const float4*)&states[sb + (size_t)p * DS + nk * 4];
      u32 lo = (u32)f2us(v.x) | ((u32)f2us(v.y) << 16);
      u32 hi = (u32)f2us(v.z) | ((u32)f2us(v.w) << 16);
      *(uint2*)&pool[SST_OFF + p * 136 + nk * 4] = make_uint2(lo, hi);
    }
  }
  __syncthreads();

  f32x4 yo[4];
#pragma unroll
  for (int i = 0; i < 4; ++i) yo[i] = (f32x4){0.f, 0.f, 0.f, 0.f};
#pragma unroll
  for (int pp4 = 0; pp4 < 4; ++pp4) {
#pragma unroll
    for (int kk = 0; kk < 4; ++kk) {
      bf16x8 ca = *(const bf16x8*)&pool[C_OFF + (wv * 16 + fr) * 128 + ((kk * 32 + oct * 8) ^ swz)];
      bf16x8 sbf = *(const bf16x8*)&pool[SST_OFF + (pp4 * 16 + fr) * 136 + kk * 32 + oct * 8];
      yo[pp4] = __builtin_amdgcn_mfma_f32_16x16x32_bf16(ca, sbf, yo[pp4], 0, 0, 0);
    }
  }

  const float Dh = Dvec[h];
#pragma unroll
  for (int i = 0; i < 4; ++i) {
    int l_tile = wv * 16 + oct * 4 + i;
    float eL = __expf(AcsL[l_tile]);
    size_t row = rowbase + lt * 64 + l_tile;
#pragma unroll
    for (int pp4 = 0; pp4 < 4; ++pp4) {
      int col = h * HD + pp4 * 16 + fr;
      float xs = us2f(xbc[row * CONVD + col]);
      float val = acc_y[pp4][i] + eL * yo[pp4][i] + Dh * xs;
      y[row * DI + col] = f2us(val);
    }
  }
}

// ---- gated RMSNorm in place on y (bf16)
__global__ __launch_bounds__(256) void gnorm_k(const u16* __restrict__ zb,
                                               const float* __restrict__ nw,
                                               u16* __restrict__ y) {
  const int row = blockIdx.x, t = threadIdx.x;
  const u16* zr = zb + (size_t)row * DI;
  u16* yr = y + (size_t)row * DI;
  uint4 zv = *(const uint4*)&zr[t * 8];
  uint4 yv = *(const uint4*)&yr[t * 8];
  float uz[8], uy[8];
  unpack8(zv, uz); unpack8(yv, uy);
  float u[8], ssum = 0.0f;
#pragma unroll
  for (int j = 0; j < 8; ++j) { u[j] = uy[j] * silu_(uz[j]); ssum += u[j] * u[j]; }
#pragma unroll
  for (int off = 32; off >= 1; off >>= 1) ssum += __shfl_xor(ssum, off, 64);
  __shared__ float red[4];
  if ((t & 63) == 0) red[t >> 6] = ssum;
  __syncthreads();
  float sc = rsqrtf((red[0] + red[1] + red[2] + red[3]) * (1.0f / DI) + 1e-5f);
  float4 w0 = *(const float4*)&nw[t * 8];
  float4 w1 = *(const float4*)&nw[t * 8 + 4];
  float o0 = u[0] * sc * w0.x, o1 = u[1] * sc * w0.y, o2 = u[2] * sc * w0.z, o3 = u[3] * sc * w0.w;
  float o4 = u[4] * sc * w1.x, o5 = u[5] * sc * w1.y, o6 = u[6] * sc * w1.z, o7 = u[7] * sc * w1.w;
  uint4 ov;
  ov.x = (u32)f2us(o0) | ((u32)f2us(o1) << 16);
  ov.y = (u32)f2us(o2) | ((u32)f2us(o3) << 16);
  ov.z = (u32)f2us(o4) | ((u32)f2us(o5) << 16);
  ov.w = (u32)f2us(o6) | ((u32)f2us(o7) << 16);
  *(uint4*)&yr[t * 8] = ov;
}

extern "C" void kernel_launch(void* const* d_in, const int* in_sizes, int n_in,
                              void* d_out, int out_size, void* d_ws, size_t ws_size,
                              hipStream_t stream) {
  const float* x      = (const float*)d_in[0];
  const float* W_in   = (const float*)d_in[1];
  const float* conv_w = (const float*)d_in[2];
  const float* conv_b = (const float*)d_in[3];
  const float* dt_b   = (const float*)d_in[4];
  const float* A_log  = (const float*)d_in[5];
  const float* Dvec   = (const float*)d_in[6];
  const float* norm_w = (const float*)d_in[7];
  const float* W_out  = (const float*)d_in[8];
  float* out = (float*)d_out;

  // workspace layout (144.7 MB total, unchanged)
  u16* zb       = (u16*)d_ws;                              // 33.55 MB
  u16* xbc      = zb + (size_t)B_ * L_ * DI;               // 37.75 MB
  float* dtp    = (float*)(xbc + (size_t)B_ * L_ * CONVD); // 1.05 MB
  float* Acs    = dtp + (size_t)B_ * L_ * NH;              // 1.05 MB
  float* states = Acs + (size_t)B_ * NH * L_;              // 33.55 MB
  u16* uni      = (u16*)(states + (size_t)B_ * NC * NH * HD * DS);  // 37.75 MB
  u16* xraw = uni;  // dead after conv
  u16* y    = uni;  // aliases xraw

  // bf16 operand buffers parked inside the (not-yet-live) states region
  u16* xb16   = (u16*)states;                      // 16.78 MB
  u16* wint   = xb16 + (size_t)B_ * L_ * DM;       //  8.91 MB  (<= 33.55 total)
  u16* woutt  = (u16*)states;                      //  4.19 MB  (after ssd_out_k)

  const int Mrows = B_ * L_;

  cvt_bf16_k<<<(Mrows * DM / 8 + 255) / 256, 256, 0, stream>>>(x, xb16, Mrows * DM / 8);
  cvt_t_k<<<dim3(NGEMM / 64, DM / 64), 256, 0, stream>>>(W_in, wint, DPROJ, DM);

  const int nwg_in = (Mrows / 128) * (NGEMM / 128);   // 64*34 = 2176
  gemm_bf16_k<DM, NGEMM / 128, 0><<<nwg_in, 256, 0, stream>>>(
      xb16, wint, zb, xraw, nullptr, nwg_in);
  dt_gemm_k<<<Mrows / 8, 256, 0, stream>>>(x, W_in, dt_b, dtp);

  conv_silu_k<<<(Mrows * CONVD) / 256, 256, 0, stream>>>(xraw, conv_w, conv_b, xbc);
  acs_k<<<4, 256, 0, stream>>>(dtp, A_log, Acs);
  states_k<<<B_ * NC * NH, 256, 0, stream>>>(xbc, dtp, Acs, states);
  scan_k<<<B_ * NH, 256, 0, stream>>>(states, Acs);
  ssd_out_k<<<B_ * NC * NH * 4, 256, 0, stream>>>(xbc, dtp, Acs, states, Dvec, y);
  gnorm_k<<<Mrows, 256, 0, stream>>>(zb, norm_w, y);

  cvt_t_k<<<dim3(DM / 64, DI / 64), 256, 0, stream>>>(W_out, woutt, DM, DI);
  const int nwg_out = (Mrows / 128) * (DM / 128);     // 64*8 = 512
  gemm_bf16_k<DI, DM / 128, 1><<<nwg_out, 256, 0, stream>>>(
      y, woutt, nullptr, nullptr, out, nwg_out);
}

// Round 6
// 411.702 us; speedup vs baseline: 20.5894x; 1.2466x over previous
//
#include <hip/hip_runtime.h>
#include <math.h>

#define B_ 2
#define L_ 4096
#define DM 1024
#define DI 2048
#define HD 64
#define NH 32
#define DS 128
#define CH 256
#define NC 16
#define DPROJ 4384   // 2*DI + 2*DS + NH
#define CONVD 2304   // DI + 2*DS
#define NGEMM 4352   // z + xBC columns (dt handled separately)

typedef unsigned short u16;
typedef unsigned int u32;
typedef __attribute__((ext_vector_type(8))) short bf16x8;
typedef __attribute__((ext_vector_type(4))) float f32x4;

__device__ __forceinline__ float silu_(float x) { return x / (1.0f + __expf(-x)); }
__device__ __forceinline__ float us2f(u16 u) {
  union { u32 i; float f; } c; c.i = ((u32)u) << 16; return c.f;
}
__device__ __forceinline__ u16 f2us(float f) {
  union { float f; u32 i; } c; c.f = f;
  u32 i = c.i;
  return (u16)((i + 0x7FFFu + ((i >> 16) & 1u)) >> 16);  // round-nearest-even
}
__device__ __forceinline__ void unpack8(uint4 v, float* o) {
  o[0] = us2f(v.x & 0xffffu); o[1] = us2f(v.x >> 16);
  o[2] = us2f(v.y & 0xffffu); o[3] = us2f(v.y >> 16);
  o[4] = us2f(v.z & 0xffffu); o[5] = us2f(v.z >> 16);
  o[6] = us2f(v.w & 0xffffu); o[7] = us2f(v.w >> 16);
}
__device__ __forceinline__ void gload16(const u16* g, u16* l) {
  __builtin_amdgcn_global_load_lds(
      (const __attribute__((address_space(1))) void*)g,
      (__attribute__((address_space(3))) void*)l, 16, 0, 0);
}

// ---- elementwise fp32 -> bf16 ----------------------------------------------
__global__ __launch_bounds__(256) void cvt_bf16_k(const float* __restrict__ in,
                                                  u16* __restrict__ out, int n8) {
  int idx = blockIdx.x * 256 + threadIdx.x;
  if (idx >= n8) return;
  const float4 a = *(const float4*)&in[idx * 8];
  const float4 b = *(const float4*)&in[idx * 8 + 4];
  uint4 v;
  v.x = (u32)f2us(a.x) | ((u32)f2us(a.y) << 16);
  v.y = (u32)f2us(a.z) | ((u32)f2us(a.w) << 16);
  v.z = (u32)f2us(b.x) | ((u32)f2us(b.y) << 16);
  v.w = (u32)f2us(b.z) | ((u32)f2us(b.w) << 16);
  *(uint4*)&out[idx * 8] = v;
}

// ---- transpose + convert: Wt[n][k] = (bf16) W[k][n] -------------------------
__global__ __launch_bounds__(256) void cvt_t_k(const float* __restrict__ W,
                                               u16* __restrict__ Wt,
                                               int ldW, int ldT) {
  __shared__ float tile[64][65];
  const int t = threadIdx.x;
  const int n0 = blockIdx.x * 64, k0 = blockIdx.y * 64;
#pragma unroll
  for (int i = 0; i < 16; ++i) {
    int j = i * 256 + t;
    int kk = j >> 6, nn = j & 63;
    tile[kk][nn] = W[(size_t)(k0 + kk) * ldW + n0 + nn];
  }
  __syncthreads();
#pragma unroll
  for (int i = 0; i < 16; ++i) {
    int j = i * 256 + t;
    int nn = j >> 6, kk = j & 63;
    Wt[(size_t)(n0 + nn) * ldT + k0 + kk] = f2us(tile[kk][nn]);
  }
}

// ---- bf16 MFMA GEMM: D = A(MxK) . Bt(NxK)^T, 128x128 tile, BK=64 -----------
template <int KDIM, int NTN, int EPI>
__global__ __launch_bounds__(256) void gemm_bf16_k(const u16* __restrict__ A,
                                                   const u16* __restrict__ Bt,
                                                   u16* __restrict__ zb,
                                                   u16* __restrict__ xraw,
                                                   float* __restrict__ outf,
                                                   int nwg) {
  __shared__ u16 pool[(EPI == 1) ? 17408 : 16384];  // 34KB (fp32 epi) / 32KB
  u16* Al = pool;          // [128][64] linear
  u16* Bl = pool + 8192;   // [128][64] linear
  const int t = threadIdx.x;
  const int wv = t >> 6, lane = t & 63;
  const int fr = lane & 15, oct = lane >> 4;
  const int wr = wv >> 1, wc = wv & 1;
  const int q = nwg >> 3;
  const int wg = (blockIdx.x & 7) * q + (blockIdx.x >> 3);
  const int bm = wg / NTN, bn = wg % NTN;
  const int m0 = bm * 128, n0 = bn * 128;

  const int lr = lane >> 3, ls = lane & 7;
  const int gslot = (ls ^ lr) * 8;   // XOR involution: LDS[r][s] = G[r][s^(r&7)]

  f32x4 acc[4][4];
#pragma unroll
  for (int mm = 0; mm < 4; ++mm)
#pragma unroll
    for (int nn = 0; nn < 4; ++nn) acc[mm][nn] = (f32x4){0.f, 0.f, 0.f, 0.f};

  for (int k0 = 0; k0 < KDIM; k0 += 64) {
    if (k0) __syncthreads();
#pragma unroll
    for (int i = 0; i < 4; ++i) {
      const int rowA = wv * 32 + i * 8;
      gload16(&A[(size_t)(m0 + rowA + lr) * KDIM + k0 + gslot], &Al[rowA * 64]);
      gload16(&Bt[(size_t)(n0 + rowA + lr) * KDIM + k0 + gslot], &Bl[rowA * 64]);
    }
    __syncthreads();
#pragma unroll
    for (int kk = 0; kk < 2; ++kk) {
      bf16x8 af[4], bfr[4];
#pragma unroll
      for (int mm = 0; mm < 4; ++mm)
        af[mm] = *(const bf16x8*)&Al[(wr * 64 + mm * 16 + fr) * 64 +
                                     (((kk * 4 + oct) ^ (fr & 7)) * 8)];
#pragma unroll
      for (int nn = 0; nn < 4; ++nn)
        bfr[nn] = *(const bf16x8*)&Bl[(wc * 64 + nn * 16 + fr) * 64 +
                                      (((kk * 4 + oct) ^ (fr & 7)) * 8)];
#pragma unroll
      for (int mm = 0; mm < 4; ++mm)
#pragma unroll
        for (int nn = 0; nn < 4; ++nn)
          acc[mm][nn] = __builtin_amdgcn_mfma_f32_16x16x32_bf16(af[mm], bfr[nn],
                                                                acc[mm][nn], 0, 0, 0);
    }
  }

  if (EPI == 0) {
    const bool isz = (n0 < DI);
#pragma unroll
    for (int P = 0; P < 2; ++P) {
      __syncthreads();
      u16* Oh = pool;  // [64][136]
      if (wr == P) {
#pragma unroll
        for (int mm = 0; mm < 4; ++mm)
#pragma unroll
          for (int i = 0; i < 4; ++i) {
            int rloc = mm * 16 + oct * 4 + i;
#pragma unroll
            for (int nn = 0; nn < 4; ++nn)
              Oh[rloc * 136 + wc * 64 + nn * 16 + fr] = f2us(acc[mm][nn][i]);
          }
      }
      __syncthreads();
#pragma unroll
      for (int p = 0; p < 4; ++p) {
        int e = p * 256 + t;
        int row = e >> 4, cs = (e & 15) * 8;
        uint4 v = *(const uint4*)&Oh[row * 136 + cs];
        size_t grow = m0 + P * 64 + row;
        int col = n0 + cs;
        if (isz) *(uint4*)&zb[grow * DI + col] = v;
        else     *(uint4*)&xraw[grow * CONVD + (col - DI)] = v;
      }
    }
  } else {
#pragma unroll
    for (int P = 0; P < 2; ++P) {
      __syncthreads();
      float* Of = (float*)pool;  // [64][132]
      if (wr == P) {
#pragma unroll
        for (int mm = 0; mm < 4; ++mm)
#pragma unroll
          for (int i = 0; i < 4; ++i) {
            int rloc = mm * 16 + oct * 4 + i;
#pragma unroll
            for (int nn = 0; nn < 4; ++nn)
              Of[rloc * 132 + wc * 64 + nn * 16 + fr] = acc[mm][nn][i];
          }
      }
      __syncthreads();
#pragma unroll
      for (int p = 0; p < 8; ++p) {
        int e = p * 256 + t;
        int row = e >> 5, c4 = (e & 31) * 4;
        float4 v = *(const float4*)&Of[row * 132 + c4];
        *(float4*)&outf[(size_t)(m0 + P * 64 + row) * DM + n0 + c4] = v;
      }
    }
  }
}

// ---- dt columns in exact fp32: dtp = softplus(x @ W_in[:,4352:] + bias) -----
__global__ __launch_bounds__(256) void dt_gemm_k(const float* __restrict__ x,
                                                 const float* __restrict__ W,
                                                 const float* __restrict__ dtb,
                                                 float* __restrict__ dtp) {
  __shared__ float xs[8 * 1024];  // 32 KB
  const int t = threadIdx.x;
  const int row0 = blockIdx.x * 8;
#pragma unroll
  for (int i = 0; i < 8; ++i) {
    int j4 = i * 256 + t;
    *(float4*)&xs[j4 * 4] = *(const float4*)&x[(size_t)row0 * DM + j4 * 4];
  }
  __syncthreads();
  const int r = t >> 5, h = t & 31;
  float a0 = 0.f, a1 = 0.f, a2 = 0.f, a3 = 0.f;
  const float* wcol = W + (DI + CONVD) + h;
  const float* xr = &xs[r * 1024];
  for (int k = 0; k < 1024; k += 4) {
    float4 xv = *(const float4*)&xr[k];
    a0 += xv.x * wcol[(size_t)(k + 0) * DPROJ];
    a1 += xv.y * wcol[(size_t)(k + 1) * DPROJ];
    a2 += xv.z * wcol[(size_t)(k + 2) * DPROJ];
    a3 += xv.w * wcol[(size_t)(k + 3) * DPROJ];
  }
  float v = (a0 + a1) + (a2 + a3) + dtb[h];
  dtp[(size_t)(row0 + r) * NH + h] = (v > 20.0f) ? v : log1pf(__expf(v));
}

// ---- causal depthwise conv(4) + SiLU, vectorized 8ch/thread -----------------
__global__ __launch_bounds__(256) void conv_silu_k(const u16* __restrict__ xraw,
                                                   const float* __restrict__ cw,
                                                   const float* __restrict__ cb,
                                                   u16* __restrict__ xbc) {
  int idx = blockIdx.x * 256 + threadIdx.x;  // Mrows * (CONVD/8)
  int ch8 = idx % (CONVD / 8);
  int bl = idx / (CONVD / 8);
  int l = bl & (L_ - 1);
  int ch = ch8 * 8;
  const u16* src = xraw + (size_t)bl * CONVD + ch;
  float a[8], o[8];
#pragma unroll
  for (int qq = 0; qq < 8; ++qq) a[qq] = cb[ch + qq];
  float w0[8], w1[8], w2[8], w3[8];
#pragma unroll
  for (int qq = 0; qq < 8; ++qq) {
    float4 w = *(const float4*)&cw[(ch + qq) * 4];
    w0[qq] = w.x; w1[qq] = w.y; w2[qq] = w.z; w3[qq] = w.w;
  }
  if (l >= 3) {
    uint4 v = *(const uint4*)&src[-3 * CONVD]; unpack8(v, o);
#pragma unroll
    for (int qq = 0; qq < 8; ++qq) a[qq] += o[qq] * w0[qq];
  }
  if (l >= 2) {
    uint4 v = *(const uint4*)&src[-2 * CONVD]; unpack8(v, o);
#pragma unroll
    for (int qq = 0; qq < 8; ++qq) a[qq] += o[qq] * w1[qq];
  }
  if (l >= 1) {
    uint4 v = *(const uint4*)&src[-CONVD]; unpack8(v, o);
#pragma unroll
    for (int qq = 0; qq < 8; ++qq) a[qq] += o[qq] * w2[qq];
  }
  {
    uint4 v = *(const uint4*)&src[0]; unpack8(v, o);
#pragma unroll
    for (int qq = 0; qq < 8; ++qq) a[qq] += o[qq] * w3[qq];
  }
  uint4 ov;
  ov.x = (u32)f2us(silu_(a[0])) | ((u32)f2us(silu_(a[1])) << 16);
  ov.y = (u32)f2us(silu_(a[2])) | ((u32)f2us(silu_(a[3])) << 16);
  ov.z = (u32)f2us(silu_(a[4])) | ((u32)f2us(silu_(a[5])) << 16);
  ov.w = (u32)f2us(silu_(a[6])) | ((u32)f2us(silu_(a[7])) << 16);
  *(uint4*)&xbc[(size_t)bl * CONVD + ch] = ov;
}

// ---- per-(b,h,c) cumsum of dt*A via wave-parallel shfl scan -----------------
__global__ __launch_bounds__(256) void acs_k(const float* __restrict__ dtp,
                                             const float* __restrict__ A_log,
                                             float* __restrict__ Acs) {
  const int t = threadIdx.x;
  const int lane = t & 63, wv = t >> 6;
  const int idx = blockIdx.x * 4 + wv;  // (b,h,c)
  const int h = (idx >> 4) & (NH - 1);
  const int c = idx & (NC - 1);
  const int b = idx >> 9;
  const float Ah = -__expf(A_log[h]);
  const size_t base = ((size_t)b * L_ + c * CH + lane * 4) * NH + h;
  float v0 = dtp[base] * Ah;
  float v1 = dtp[base + NH] * Ah;
  float v2 = dtp[base + 2 * NH] * Ah;
  float v3 = dtp[base + 3 * NH] * Ah;
  float c1 = v0 + v1, c2 = c1 + v2, c3 = c2 + v3;
  float tot = c3;
#pragma unroll
  for (int off = 1; off < 64; off <<= 1) {
    float p = __shfl_up(tot, off, 64);
    if (lane >= off) tot += p;
  }
  float excl = tot - c3;
  float4 ov = make_float4(excl + v0, excl + c1, excl + c2, excl + c3);
  *(float4*)&Acs[(size_t)idx * CH + lane * 4] = ov;
}

// ---- chunk end-states via MFMA: states[b,c,h,p,n] fp32 ----------------------
// Bt tile [128 n][64 l], Xt tile [64 p][64 l]: pad-72 rows, 8-u16 groups
// XOR-swizzled by (l>>3)^(row>>3) -> conflict-free b128 reads, ~2-way writes.
#define SLP 72
__global__ __launch_bounds__(256) void states_k(const u16* __restrict__ xbc,
                                                const float* __restrict__ dtp,
                                                const float* __restrict__ Acs,
                                                float* __restrict__ states) {
  __shared__ u16 BtT[128 * SLP];
  __shared__ u16 XtT[64 * SLP];
  const int t = threadIdx.x;
  const int wv = t >> 6, lane = t & 63;
  const int fr = lane & 15, oct = lane >> 4;
  const int h = blockIdx.x & 31, c = (blockIdx.x >> 5) & 15, b = blockIdx.x >> 9;
  const size_t acsb = (((size_t)b * NH + h) * NC + c) * CH;
  const float acs_last = Acs[acsb + (CH - 1)];
  const size_t rowbase = (size_t)b * L_ + c * CH;

  f32x4 acc[2][4];
#pragma unroll
  for (int mt = 0; mt < 2; ++mt)
#pragma unroll
    for (int pt = 0; pt < 4; ++pt) acc[mt][pt] = (f32x4){0.f, 0.f, 0.f, 0.f};

  for (int lt = 0; lt < 4; ++lt) {
    __syncthreads();  // previous iteration's fragment reads complete
    // stage Bt[n][l] = B[l][n]  (raw bf16 copy, transposed)
#pragma unroll
    for (int i = 0; i < 4; ++i) {
      int ci = i * 256 + t;
      int l = ci >> 4, nk = ci & 15;
      uint4 v = *(const uint4*)&xbc[(rowbase + lt * 64 + l) * CONVD + DI + nk * 8];
      u16 p8[8];
      p8[0] = (u16)(v.x & 0xffffu); p8[1] = (u16)(v.x >> 16);
      p8[2] = (u16)(v.y & 0xffffu); p8[3] = (u16)(v.y >> 16);
      p8[4] = (u16)(v.z & 0xffffu); p8[5] = (u16)(v.z >> 16);
      p8[6] = (u16)(v.w & 0xffffu); p8[7] = (u16)(v.w >> 16);
#pragma unroll
      for (int qq = 0; qq < 8; ++qq) {
        int r = nk * 8 + qq;
        BtT[r * SLP + ((((l >> 3) ^ (r >> 3)) & 7) << 3) + (l & 7)] = p8[qq];
      }
    }
    // stage Xt[p][l] = x[l][p]*dt[l]*wdec[l]
#pragma unroll
    for (int i = 0; i < 2; ++i) {
      int ci = i * 256 + t;
      int l = ci >> 3, pk = ci & 7;
      size_t row = rowbase + lt * 64 + l;
      uint4 v = *(const uint4*)&xbc[row * CONVD + h * HD + pk * 8];
      float d = dtp[row * NH + h] * __expf(acs_last - Acs[acsb + lt * 64 + l]);
      float o[8]; unpack8(v, o);
#pragma unroll
      for (int qq = 0; qq < 8; ++qq) {
        int r = pk * 8 + qq;
        XtT[r * SLP + ((((l >> 3) ^ (r >> 3)) & 7) << 3) + (l & 7)] = f2us(o[qq] * d);
      }
    }
    __syncthreads();
    // D[n][p] += sum_l Bt[n][l] * Xt[p][l]
#pragma unroll
    for (int ks = 0; ks < 2; ++ks) {
      bf16x8 afr[2], bfr[4];
#pragma unroll
      for (int mt = 0; mt < 2; ++mt) {
        int r = wv * 32 + mt * 16 + fr;
        afr[mt] = *(const bf16x8*)&BtT[r * SLP + ((((ks * 4 + oct) ^ (r >> 3)) & 7) << 3)];
      }
#pragma unroll
      for (int pt = 0; pt < 4; ++pt) {
        int r = pt * 16 + fr;
        bfr[pt] = *(const bf16x8*)&XtT[r * SLP + ((((ks * 4 + oct) ^ (r >> 3)) & 7) << 3)];
      }
#pragma unroll
      for (int mt = 0; mt < 2; ++mt)
#pragma unroll
        for (int pt = 0; pt < 4; ++pt)
          acc[mt][pt] = __builtin_amdgcn_mfma_f32_16x16x32_bf16(afr[mt], bfr[pt],
                                                                acc[mt][pt], 0, 0, 0);
    }
  }
  // store: D row = n, D col (fr) = p; consecutive regs i -> consecutive n
  size_t sbase = (((size_t)b * NC + c) * NH + h) * (size_t)(HD * DS);
#pragma unroll
  for (int mt = 0; mt < 2; ++mt)
#pragma unroll
    for (int pt = 0; pt < 4; ++pt) {
      int p = pt * 16 + fr;
      int n0 = wv * 32 + mt * 16 + oct * 4;
      *(f32x4*)&states[sbase + (size_t)p * DS + n0] = acc[mt][pt];
    }
}

// ---- inter-chunk scan: one thread per state element -------------------------
__global__ __launch_bounds__(256) void scan_k(float* __restrict__ states,
                                              const float* __restrict__ Acs) {
  const int t = threadIdx.x;
  const int seg = blockIdx.x & 31;
  const int bh = blockIdx.x >> 5;
  const int h = bh & 31, b = bh >> 5;
  const int elem = seg * 256 + t;
  const size_t acssb = ((size_t)b * NH + h) * NC * CH;
  float run = 0.0f;
#pragma unroll
  for (int c = 0; c < NC; ++c) {
    float dAl = __expf(Acs[acssb + (size_t)c * CH + (CH - 1)]);
    size_t e = (((size_t)b * NC + c) * NH + h) * (size_t)(HD * DS) + elem;
    float s = states[e];
    states[e] = run;
    run = fmaf(dAl, run, s);
  }
}

// ---- intra-chunk + state-output via MFMA 16x16x32 bf16 ----------------------
#define C_OFF 0
#define B_OFF 8192
#define XT_OFF 16384
#define PL_OFF 20992
#define SST_OFF 8192
#define POOL_SZ 25600

__global__ __launch_bounds__(256) void ssd_out_k(const u16* __restrict__ xbc,
                                                 const float* __restrict__ dtp,
                                                 const float* __restrict__ Acs,
                                                 const float* __restrict__ states,
                                                 const float* __restrict__ Dvec,
                                                 u16* __restrict__ y) {
  __shared__ u16 pool[POOL_SZ];
  __shared__ float AcsL[64];
  __shared__ float AcsS[64];
  const int t = threadIdx.x;
  const int wv = t >> 6, lane = t & 63;
  const int lt = blockIdx.x & 3;
  const int h = (blockIdx.x >> 2) & 31;
  const int c = (blockIdx.x >> 7) & 15;
  const int b = blockIdx.x >> 11;
  const size_t acsb = (((size_t)b * NH + h) * NC + c) * CH;
  const size_t rowbase = (size_t)b * L_ + c * CH;

  const int fr = lane & 15;
  const int oct = lane >> 4;
  const int swz = (fr & 7) << 3;

#pragma unroll
  for (int i = 0; i < 4; ++i) {
    int ci = i * 256 + t; int ll = ci >> 4, ck = ci & 15;
    size_t row = rowbase + lt * 64 + ll;
    uint4 v = *(const uint4*)&xbc[row * CONVD + DI + DS + ck * 8];
    *(uint4*)&pool[C_OFF + ll * 128 + ((ck * 8) ^ ((ll & 7) << 3))] = v;
  }
  if (t < 64) AcsL[t] = Acs[acsb + lt * 64 + t];

  f32x4 acc_y[4];
#pragma unroll
  for (int i = 0; i < 4; ++i) acc_y[i] = (f32x4){0.f, 0.f, 0.f, 0.f};

  for (int st = 0; st <= lt; ++st) {
#pragma unroll
    for (int i = 0; i < 4; ++i) {
      int ci = i * 256 + t; int ll = ci >> 4, ck = ci & 15;
      size_t row = rowbase + st * 64 + ll;
      uint4 v = *(const uint4*)&xbc[row * CONVD + DI + ck * 8];
      *(uint4*)&pool[B_OFF + ll * 128 + ((ck * 8) ^ ((ll & 7) << 3))] = v;
    }
#pragma unroll
    for (int i = 0; i < 2; ++i) {
      int ci = i * 256 + t; int s = ci >> 3, pk = ci & 7;
      size_t row = rowbase + st * 64 + s;
      uint4 v = *(const uint4*)&xbc[row * CONVD + h * HD + pk * 8];
      float d = dtp[row * NH + h];
      float o[8]; unpack8(v, o);
#pragma unroll
      for (int qq = 0; qq < 8; ++qq) pool[XT_OFF + (pk * 8 + qq) * 72 + s] = f2us(o[qq] * d);
    }
    if (t < 64) AcsS[t] = Acs[acsb + st * 64 + t];
    __syncthreads();

#pragma unroll
    for (int ss4 = 0; ss4 < 4; ++ss4) {
      f32x4 sacc = (f32x4){0.f, 0.f, 0.f, 0.f};
#pragma unroll
      for (int kk = 0; kk < 4; ++kk) {
        bf16x8 ca = *(const bf16x8*)&pool[C_OFF + (wv * 16 + fr) * 128 + ((kk * 32 + oct * 8) ^ swz)];
        bf16x8 bb = *(const bf16x8*)&pool[B_OFF + (ss4 * 16 + fr) * 128 + ((kk * 32 + oct * 8) ^ swz)];
        sacc = __builtin_amdgcn_mfma_f32_16x16x32_bf16(ca, bb, sacc, 0, 0, 0);
      }
      float aS = AcsS[ss4 * 16 + fr];
      int s_tile = ss4 * 16 + fr;
#pragma unroll
      for (int i = 0; i < 4; ++i) {
        int r = oct * 4 + i;
        int l_tile = wv * 16 + r;
        float aL = AcsL[l_tile];
        float wgt = ((st < lt) || (s_tile <= l_tile)) ? __expf(aL - aS) : 0.0f;
        pool[PL_OFF + wv * 1152 + r * 72 + s_tile] = f2us(sacc[i] * wgt);
      }
    }
#pragma unroll
    for (int pp4 = 0; pp4 < 4; ++pp4) {
#pragma unroll
      for (int kk2 = 0; kk2 < 2; ++kk2) {
        bf16x8 pa = *(const bf16x8*)&pool[PL_OFF + wv * 1152 + fr * 72 + kk2 * 32 + oct * 8];
        bf16x8 xb = *(const bf16x8*)&pool[XT_OFF + (pp4 * 16 + fr) * 72 + kk2 * 32 + oct * 8];
        acc_y[pp4] = __builtin_amdgcn_mfma_f32_16x16x32_bf16(pa, xb, acc_y[pp4], 0, 0, 0);
      }
    }
    __syncthreads();
  }

  {
    size_t sb = (((size_t)b * NC + c) * NH + h) * (size_t)(HD * DS);
#pragma unroll
    for (int i = 0; i < 8; ++i) {
      int ci = i * 256 + t; int p = ci >> 5, nk = ci & 31;
      float4 v = *(const float4*)&states[sb + (size_t)p * DS + nk * 4];
      u32 lo = (u32)f2us(v.x) | ((u32)f2us(v.y) << 16);
      u32 hi = (u32)f2us(v.z) | ((u32)f2us(v.w) << 16);
      *(uint2*)&pool[SST_OFF + p * 136 + nk * 4] = make_uint2(lo, hi);
    }
  }
  __syncthreads();

  f32x4 yo[4];
#pragma unroll
  for (int i = 0; i < 4; ++i) yo[i] = (f32x4){0.f, 0.f, 0.f, 0.f};
#pragma unroll
  for (int pp4 = 0; pp4 < 4; ++pp4) {
#pragma unroll
    for (int kk = 0; kk < 4; ++kk) {
      bf16x8 ca = *(const bf16x8*)&pool[C_OFF + (wv * 16 + fr) * 128 + ((kk * 32 + oct * 8) ^ swz)];
      bf16x8 sbf = *(const bf16x8*)&pool[SST_OFF + (pp4 * 16 + fr) * 136 + kk * 32 + oct * 8];
      yo[pp4] = __builtin_amdgcn_mfma_f32_16x16x32_bf16(ca, sbf, yo[pp4], 0, 0, 0);
    }
  }

  const float Dh = Dvec[h];
#pragma unroll
  for (int i = 0; i < 4; ++i) {
    int l_tile = wv * 16 + oct * 4 + i;
    float eL = __expf(AcsL[l_tile]);
    size_t row = rowbase + lt * 64 + l_tile;
#pragma unroll
    for (int pp4 = 0; pp4 < 4; ++pp4) {
      int col = h * HD + pp4 * 16 + fr;
      float xs = us2f(xbc[row * CONVD + col]);
      float val = acc_y[pp4][i] + eL * yo[pp4][i] + Dh * xs;
      y[row * DI + col] = f2us(val);
    }
  }
}

// ---- gated RMSNorm in place on y (bf16)
__global__ __launch_bounds__(256) void gnorm_k(const u16* __restrict__ zb,
                                               const float* __restrict__ nw,
                                               u16* __restrict__ y) {
  const int row = blockIdx.x, t = threadIdx.x;
  const u16* zr = zb + (size_t)row * DI;
  u16* yr = y + (size_t)row * DI;
  uint4 zv = *(const uint4*)&zr[t * 8];
  uint4 yv = *(const uint4*)&yr[t * 8];
  float uz[8], uy[8];
  unpack8(zv, uz); unpack8(yv, uy);
  float u[8], ssum = 0.0f;
#pragma unroll
  for (int j = 0; j < 8; ++j) { u[j] = uy[j] * silu_(uz[j]); ssum += u[j] * u[j]; }
#pragma unroll
  for (int off = 32; off >= 1; off >>= 1) ssum += __shfl_xor(ssum, off, 64);
  __shared__ float red[4];
  if ((t & 63) == 0) red[t >> 6] = ssum;
  __syncthreads();
  float sc = rsqrtf((red[0] + red[1] + red[2] + red[3]) * (1.0f / DI) + 1e-5f);
  float4 w0 = *(const float4*)&nw[t * 8];
  float4 w1 = *(const float4*)&nw[t * 8 + 4];
  float o0 = u[0] * sc * w0.x, o1 = u[1] * sc * w0.y, o2 = u[2] * sc * w0.z, o3 = u[3] * sc * w0.w;
  float o4 = u[4] * sc * w1.x, o5 = u[5] * sc * w1.y, o6 = u[6] * sc * w1.z, o7 = u[7] * sc * w1.w;
  uint4 ov;
  ov.x = (u32)f2us(o0) | ((u32)f2us(o1) << 16);
  ov.y = (u32)f2us(o2) | ((u32)f2us(o3) << 16);
  ov.z = (u32)f2us(o4) | ((u32)f2us(o5) << 16);
  ov.w = (u32)f2us(o6) | ((u32)f2us(o7) << 16);
  *(uint4*)&yr[t * 8] = ov;
}

extern "C" void kernel_launch(void* const* d_in, const int* in_sizes, int n_in,
                              void* d_out, int out_size, void* d_ws, size_t ws_size,
                              hipStream_t stream) {
  const float* x      = (const float*)d_in[0];
  const float* W_in   = (const float*)d_in[1];
  const float* conv_w = (const float*)d_in[2];
  const float* conv_b = (const float*)d_in[3];
  const float* dt_b   = (const float*)d_in[4];
  const float* A_log  = (const float*)d_in[5];
  const float* Dvec   = (const float*)d_in[6];
  const float* norm_w = (const float*)d_in[7];
  const float* W_out  = (const float*)d_in[8];
  float* out = (float*)d_out;

  // workspace layout (144.7 MB total, unchanged)
  u16* zb       = (u16*)d_ws;                              // 33.55 MB
  u16* xbc      = zb + (size_t)B_ * L_ * DI;               // 37.75 MB
  float* dtp    = (float*)(xbc + (size_t)B_ * L_ * CONVD); // 1.05 MB
  float* Acs    = dtp + (size_t)B_ * L_ * NH;              // 1.05 MB
  float* states = Acs + (size_t)B_ * NH * L_;              // 33.55 MB
  u16* uni      = (u16*)(states + (size_t)B_ * NC * NH * HD * DS);  // 37.75 MB
  u16* xraw = uni;  // dead after conv
  u16* y    = uni;  // aliases xraw

  // bf16 operand buffers parked inside the (not-yet-live) states region
  u16* xb16   = (u16*)states;                      // 16.78 MB
  u16* wint   = xb16 + (size_t)B_ * L_ * DM;       //  8.91 MB
  u16* woutt  = (u16*)states;                      //  4.19 MB  (after ssd_out_k)

  const int Mrows = B_ * L_;

  cvt_bf16_k<<<(Mrows * DM / 8 + 255) / 256, 256, 0, stream>>>(x, xb16, Mrows * DM / 8);
  cvt_t_k<<<dim3(NGEMM / 64, DM / 64), 256, 0, stream>>>(W_in, wint, DPROJ, DM);

  const int nwg_in = (Mrows / 128) * (NGEMM / 128);   // 2176
  gemm_bf16_k<DM, NGEMM / 128, 0><<<nwg_in, 256, 0, stream>>>(
      xb16, wint, zb, xraw, nullptr, nwg_in);
  dt_gemm_k<<<Mrows / 8, 256, 0, stream>>>(x, W_in, dt_b, dtp);

  conv_silu_k<<<(Mrows * (CONVD / 8)) / 256, 256, 0, stream>>>(xraw, conv_w, conv_b, xbc);
  acs_k<<<(B_ * NH * NC) / 4, 256, 0, stream>>>(dtp, A_log, Acs);
  states_k<<<B_ * NC * NH, 256, 0, stream>>>(xbc, dtp, Acs, states);
  scan_k<<<B_ * NH * 32, 256, 0, stream>>>(states, Acs);
  ssd_out_k<<<B_ * NC * NH * 4, 256, 0, stream>>>(xbc, dtp, Acs, states, Dvec, y);
  gnorm_k<<<Mrows, 256, 0, stream>>>(zb, norm_w, y);

  cvt_t_k<<<dim3(DM / 64, DI / 64), 256, 0, stream>>>(W_out, woutt, DM, DI);
  const int nwg_out = (Mrows / 128) * (DM / 128);     // 512
  gemm_bf16_k<DI, DM / 128, 1><<<nwg_out, 256, 0, stream>>>(
      y, woutt, nullptr, nullptr, out, nwg_out);
}

// Round 7
// 361.489 us; speedup vs baseline: 23.4494x; 1.1389x over previous
//
#include <hip/hip_runtime.h>
#include <math.h>

#define B_ 2
#define L_ 4096
#define DM 1024
#define DI 2048
#define HD 64
#define NH 32
#define DS 128
#define CH 256
#define NC 16
#define DPROJ 4384   // 2*DI + 2*DS + NH
#define CONVD 2304   // DI + 2*DS
#define NGEMM 4352   // z + xBC columns (dt handled separately)

typedef unsigned short u16;
typedef unsigned int u32;
typedef __attribute__((ext_vector_type(8))) short bf16x8;
typedef __attribute__((ext_vector_type(4))) float f32x4;

__device__ __forceinline__ float silu_(float x) { return x / (1.0f + __expf(-x)); }
__device__ __forceinline__ float us2f(u16 u) {
  union { u32 i; float f; } c; c.i = ((u32)u) << 16; return c.f;
}
__device__ __forceinline__ u16 f2us(float f) {
  union { float f; u32 i; } c; c.f = f;
  u32 i = c.i;
  return (u16)((i + 0x7FFFu + ((i >> 16) & 1u)) >> 16);  // round-nearest-even
}
__device__ __forceinline__ void unpack8(uint4 v, float* o) {
  o[0] = us2f(v.x & 0xffffu); o[1] = us2f(v.x >> 16);
  o[2] = us2f(v.y & 0xffffu); o[3] = us2f(v.y >> 16);
  o[4] = us2f(v.z & 0xffffu); o[5] = us2f(v.z >> 16);
  o[6] = us2f(v.w & 0xffffu); o[7] = us2f(v.w >> 16);
}
__device__ __forceinline__ bf16x8 scale8(bf16x8 a, float s) {
  bf16x8 r;
#pragma unroll
  for (int j = 0; j < 8; ++j) r[j] = (short)f2us(us2f((u16)a[j]) * s);
  return r;
}
__device__ __forceinline__ void gload16(const u16* g, u16* l) {
  __builtin_amdgcn_global_load_lds(
      (const __attribute__((address_space(1))) void*)g,
      (__attribute__((address_space(3))) void*)l, 16, 0, 0);
}

// ---- transpose + convert: Wt[n][k] = (bf16) W[k][n] -------------------------
__global__ __launch_bounds__(256) void cvt_t_k(const float* __restrict__ W,
                                               u16* __restrict__ Wt,
                                               int ldW, int ldT) {
  __shared__ float tile[64][65];
  const int t = threadIdx.x;
  const int n0 = blockIdx.x * 64, k0 = blockIdx.y * 64;
#pragma unroll
  for (int i = 0; i < 16; ++i) {
    int j = i * 256 + t;
    int kk = j >> 6, nn = j & 63;
    tile[kk][nn] = W[(size_t)(k0 + kk) * ldW + n0 + nn];
  }
  __syncthreads();
#pragma unroll
  for (int i = 0; i < 16; ++i) {
    int j = i * 256 + t;
    int nn = j >> 6, kk = j & 63;
    Wt[(size_t)(n0 + nn) * ldT + k0 + kk] = f2us(tile[kk][nn]);
  }
}

// ---- bf16 MFMA GEMM: D = A(MxK) . Bt(NxK)^T, 128x128 tile, BK=64 -----------
template <int KDIM, int NTN, int EPI>
__global__ __launch_bounds__(256) void gemm_bf16_k(const u16* __restrict__ A,
                                                   const u16* __restrict__ Bt,
                                                   u16* __restrict__ zb,
                                                   u16* __restrict__ xraw,
                                                   float* __restrict__ outf,
                                                   int nwg) {
  __shared__ u16 pool[(EPI == 1) ? 17408 : 16384];  // 34KB (fp32 epi) / 32KB
  u16* Al = pool;          // [128][64] linear
  u16* Bl = pool + 8192;   // [128][64] linear
  const int t = threadIdx.x;
  const int wv = t >> 6, lane = t & 63;
  const int fr = lane & 15, oct = lane >> 4;
  const int wr = wv >> 1, wc = wv & 1;
  const int q = nwg >> 3;
  const int wg = (blockIdx.x & 7) * q + (blockIdx.x >> 3);
  const int bm = wg / NTN, bn = wg % NTN;
  const int m0 = bm * 128, n0 = bn * 128;

  const int lr = lane >> 3, ls = lane & 7;
  const int gslot = (ls ^ lr) * 8;   // XOR involution: LDS[r][s] = G[r][s^(r&7)]

  f32x4 acc[4][4];
#pragma unroll
  for (int mm = 0; mm < 4; ++mm)
#pragma unroll
    for (int nn = 0; nn < 4; ++nn) acc[mm][nn] = (f32x4){0.f, 0.f, 0.f, 0.f};

  for (int k0 = 0; k0 < KDIM; k0 += 64) {
    if (k0) __syncthreads();
#pragma unroll
    for (int i = 0; i < 4; ++i) {
      const int rowA = wv * 32 + i * 8;
      gload16(&A[(size_t)(m0 + rowA + lr) * KDIM + k0 + gslot], &Al[rowA * 64]);
      gload16(&Bt[(size_t)(n0 + rowA + lr) * KDIM + k0 + gslot], &Bl[rowA * 64]);
    }
    __syncthreads();
#pragma unroll
    for (int kk = 0; kk < 2; ++kk) {
      bf16x8 af[4], bfr[4];
#pragma unroll
      for (int mm = 0; mm < 4; ++mm)
        af[mm] = *(const bf16x8*)&Al[(wr * 64 + mm * 16 + fr) * 64 +
                                     (((kk * 4 + oct) ^ (fr & 7)) * 8)];
#pragma unroll
      for (int nn = 0; nn < 4; ++nn)
        bfr[nn] = *(const bf16x8*)&Bl[(wc * 64 + nn * 16 + fr) * 64 +
                                      (((kk * 4 + oct) ^ (fr & 7)) * 8)];
#pragma unroll
      for (int mm = 0; mm < 4; ++mm)
#pragma unroll
        for (int nn = 0; nn < 4; ++nn)
          acc[mm][nn] = __builtin_amdgcn_mfma_f32_16x16x32_bf16(af[mm], bfr[nn],
                                                                acc[mm][nn], 0, 0, 0);
    }
  }

  if (EPI == 0) {
    const bool isz = (n0 < DI);
#pragma unroll
    for (int P = 0; P < 2; ++P) {
      __syncthreads();
      u16* Oh = pool;  // [64][136]
      if (wr == P) {
#pragma unroll
        for (int mm = 0; mm < 4; ++mm)
#pragma unroll
          for (int i = 0; i < 4; ++i) {
            int rloc = mm * 16 + oct * 4 + i;
#pragma unroll
            for (int nn = 0; nn < 4; ++nn)
              Oh[rloc * 136 + wc * 64 + nn * 16 + fr] = f2us(acc[mm][nn][i]);
          }
      }
      __syncthreads();
#pragma unroll
      for (int p = 0; p < 4; ++p) {
        int e = p * 256 + t;
        int row = e >> 4, cs = (e & 15) * 8;
        uint4 v = *(const uint4*)&Oh[row * 136 + cs];
        size_t grow = m0 + P * 64 + row;
        int col = n0 + cs;
        if (isz) *(uint4*)&zb[grow * DI + col] = v;
        else     *(uint4*)&xraw[grow * CONVD + (col - DI)] = v;
      }
    }
  } else {
#pragma unroll
    for (int P = 0; P < 2; ++P) {
      __syncthreads();
      float* Of = (float*)pool;  // [64][132]
      if (wr == P) {
#pragma unroll
        for (int mm = 0; mm < 4; ++mm)
#pragma unroll
          for (int i = 0; i < 4; ++i) {
            int rloc = mm * 16 + oct * 4 + i;
#pragma unroll
            for (int nn = 0; nn < 4; ++nn)
              Of[rloc * 132 + wc * 64 + nn * 16 + fr] = acc[mm][nn][i];
          }
      }
      __syncthreads();
#pragma unroll
      for (int p = 0; p < 8; ++p) {
        int e = p * 256 + t;
        int row = e >> 5, c4 = (e & 31) * 4;
        float4 v = *(const float4*)&Of[row * 132 + c4];
        *(float4*)&outf[(size_t)(m0 + P * 64 + row) * DM + n0 + c4] = v;
      }
    }
  }
}

// ---- dt (fp32 exact) + x->bf16 fused: dtp = softplus(x @ W[:,4352:] + b) ----
__global__ __launch_bounds__(256) void dt_gemm_k(const float* __restrict__ x,
                                                 const float* __restrict__ W,
                                                 const float* __restrict__ dtb,
                                                 float* __restrict__ dtp,
                                                 u16* __restrict__ xb16) {
  __shared__ float xs[8 * 1024];  // 32 KB
  const int t = threadIdx.x;
  const int row0 = blockIdx.x * 8;
#pragma unroll
  for (int i = 0; i < 8; ++i) {
    int j4 = i * 256 + t;
    float4 v = *(const float4*)&x[(size_t)row0 * DM + j4 * 4];
    *(float4*)&xs[j4 * 4] = v;
    u32 lo = (u32)f2us(v.x) | ((u32)f2us(v.y) << 16);
    u32 hi = (u32)f2us(v.z) | ((u32)f2us(v.w) << 16);
    *(uint2*)&xb16[(size_t)row0 * DM + j4 * 4] = make_uint2(lo, hi);
  }
  __syncthreads();
  const int r = t >> 5, h = t & 31;
  float a0 = 0.f, a1 = 0.f, a2 = 0.f, a3 = 0.f;
  const float* wcol = W + (DI + CONVD) + h;
  const float* xr = &xs[r * 1024];
  for (int k = 0; k < 1024; k += 4) {
    float4 xv = *(const float4*)&xr[k];
    a0 += xv.x * wcol[(size_t)(k + 0) * DPROJ];
    a1 += xv.y * wcol[(size_t)(k + 1) * DPROJ];
    a2 += xv.z * wcol[(size_t)(k + 2) * DPROJ];
    a3 += xv.w * wcol[(size_t)(k + 3) * DPROJ];
  }
  float v = (a0 + a1) + (a2 + a3) + dtb[h];
  dtp[(size_t)(row0 + r) * NH + h] = (v > 20.0f) ? v : log1pf(__expf(v));
}

// ---- causal depthwise conv(4) + SiLU, vectorized 8ch/thread -----------------
__global__ __launch_bounds__(256) void conv_silu_k(const u16* __restrict__ xraw,
                                                   const float* __restrict__ cw,
                                                   const float* __restrict__ cb,
                                                   u16* __restrict__ xbc) {
  int idx = blockIdx.x * 256 + threadIdx.x;  // Mrows * (CONVD/8)
  int ch8 = idx % (CONVD / 8);
  int bl = idx / (CONVD / 8);
  int l = bl & (L_ - 1);
  int ch = ch8 * 8;
  const u16* src = xraw + (size_t)bl * CONVD + ch;
  float a[8], o[8];
#pragma unroll
  for (int qq = 0; qq < 8; ++qq) a[qq] = cb[ch + qq];
  float w0[8], w1[8], w2[8], w3[8];
#pragma unroll
  for (int qq = 0; qq < 8; ++qq) {
    float4 w = *(const float4*)&cw[(ch + qq) * 4];
    w0[qq] = w.x; w1[qq] = w.y; w2[qq] = w.z; w3[qq] = w.w;
  }
  if (l >= 3) {
    uint4 v = *(const uint4*)&src[-3 * CONVD]; unpack8(v, o);
#pragma unroll
    for (int qq = 0; qq < 8; ++qq) a[qq] += o[qq] * w0[qq];
  }
  if (l >= 2) {
    uint4 v = *(const uint4*)&src[-2 * CONVD]; unpack8(v, o);
#pragma unroll
    for (int qq = 0; qq < 8; ++qq) a[qq] += o[qq] * w1[qq];
  }
  if (l >= 1) {
    uint4 v = *(const uint4*)&src[-CONVD]; unpack8(v, o);
#pragma unroll
    for (int qq = 0; qq < 8; ++qq) a[qq] += o[qq] * w2[qq];
  }
  {
    uint4 v = *(const uint4*)&src[0]; unpack8(v, o);
#pragma unroll
    for (int qq = 0; qq < 8; ++qq) a[qq] += o[qq] * w3[qq];
  }
  uint4 ov;
  ov.x = (u32)f2us(silu_(a[0])) | ((u32)f2us(silu_(a[1])) << 16);
  ov.y = (u32)f2us(silu_(a[2])) | ((u32)f2us(silu_(a[3])) << 16);
  ov.z = (u32)f2us(silu_(a[4])) | ((u32)f2us(silu_(a[5])) << 16);
  ov.w = (u32)f2us(silu_(a[6])) | ((u32)f2us(silu_(a[7])) << 16);
  *(uint4*)&xbc[(size_t)bl * CONVD + ch] = ov;
}

// ---- per-(b,h,c) cumsum of dt*A via wave-parallel shfl scan -----------------
__global__ __launch_bounds__(256) void acs_k(const float* __restrict__ dtp,
                                             const float* __restrict__ A_log,
                                             float* __restrict__ Acs) {
  const int t = threadIdx.x;
  const int lane = t & 63, wv = t >> 6;
  const int idx = blockIdx.x * 4 + wv;  // (b,h,c)
  const int h = (idx >> 4) & (NH - 1);
  const int c = idx & (NC - 1);
  const int b = idx >> 9;
  const float Ah = -__expf(A_log[h]);
  const size_t base = ((size_t)b * L_ + c * CH + lane * 4) * NH + h;
  float v0 = dtp[base] * Ah;
  float v1 = dtp[base + NH] * Ah;
  float v2 = dtp[base + 2 * NH] * Ah;
  float v3 = dtp[base + 3 * NH] * Ah;
  float c1 = v0 + v1, c2 = c1 + v2, c3 = c2 + v3;
  float tot = c3;
#pragma unroll
  for (int off = 1; off < 64; off <<= 1) {
    float p = __shfl_up(tot, off, 64);
    if (lane >= off) tot += p;
  }
  float excl = tot - c3;
  float4 ov = make_float4(excl + v0, excl + c1, excl + c2, excl + c3);
  *(float4*)&Acs[(size_t)idx * CH + lane * 4] = ov;
}

// ---- chunk end-states via MFMA -> bf16 states[b,c,h,p,n] --------------------
#define SLP 72
__global__ __launch_bounds__(256) void states_k(const u16* __restrict__ xbc,
                                                const float* __restrict__ dtp,
                                                const float* __restrict__ Acs,
                                                u16* __restrict__ st16) {
  __shared__ u16 BtT[128 * SLP];
  __shared__ u16 XtT[64 * SLP];
  const int t = threadIdx.x;
  const int wv = t >> 6, lane = t & 63;
  const int fr = lane & 15, oct = lane >> 4;
  const int h = blockIdx.x & 31, c = (blockIdx.x >> 5) & 15, b = blockIdx.x >> 9;
  const size_t acsb = (((size_t)b * NH + h) * NC + c) * CH;
  const float acs_last = Acs[acsb + (CH - 1)];
  const size_t rowbase = (size_t)b * L_ + c * CH;

  f32x4 acc[2][4];
#pragma unroll
  for (int mt = 0; mt < 2; ++mt)
#pragma unroll
    for (int pt = 0; pt < 4; ++pt) acc[mt][pt] = (f32x4){0.f, 0.f, 0.f, 0.f};

  for (int lt = 0; lt < 4; ++lt) {
    __syncthreads();
#pragma unroll
    for (int i = 0; i < 4; ++i) {
      int ci = i * 256 + t;
      int l = ci >> 4, nk = ci & 15;
      uint4 v = *(const uint4*)&xbc[(rowbase + lt * 64 + l) * CONVD + DI + nk * 8];
      u16 p8[8];
      p8[0] = (u16)(v.x & 0xffffu); p8[1] = (u16)(v.x >> 16);
      p8[2] = (u16)(v.y & 0xffffu); p8[3] = (u16)(v.y >> 16);
      p8[4] = (u16)(v.z & 0xffffu); p8[5] = (u16)(v.z >> 16);
      p8[6] = (u16)(v.w & 0xffffu); p8[7] = (u16)(v.w >> 16);
#pragma unroll
      for (int qq = 0; qq < 8; ++qq) {
        int r = nk * 8 + qq;
        BtT[r * SLP + ((((l >> 3) ^ (r >> 3)) & 7) << 3) + (l & 7)] = p8[qq];
      }
    }
#pragma unroll
    for (int i = 0; i < 2; ++i) {
      int ci = i * 256 + t;
      int l = ci >> 3, pk = ci & 7;
      size_t row = rowbase + lt * 64 + l;
      uint4 v = *(const uint4*)&xbc[row * CONVD + h * HD + pk * 8];
      float d = dtp[row * NH + h] * __expf(acs_last - Acs[acsb + lt * 64 + l]);
      float o[8]; unpack8(v, o);
#pragma unroll
      for (int qq = 0; qq < 8; ++qq) {
        int r = pk * 8 + qq;
        XtT[r * SLP + ((((l >> 3) ^ (r >> 3)) & 7) << 3) + (l & 7)] = f2us(o[qq] * d);
      }
    }
    __syncthreads();
#pragma unroll
    for (int ks = 0; ks < 2; ++ks) {
      bf16x8 afr[2], bfr[4];
#pragma unroll
      for (int mt = 0; mt < 2; ++mt) {
        int r = wv * 32 + mt * 16 + fr;
        afr[mt] = *(const bf16x8*)&BtT[r * SLP + ((((ks * 4 + oct) ^ (r >> 3)) & 7) << 3)];
      }
#pragma unroll
      for (int pt = 0; pt < 4; ++pt) {
        int r = pt * 16 + fr;
        bfr[pt] = *(const bf16x8*)&XtT[r * SLP + ((((ks * 4 + oct) ^ (r >> 3)) & 7) << 3)];
      }
#pragma unroll
      for (int mt = 0; mt < 2; ++mt)
#pragma unroll
        for (int pt = 0; pt < 4; ++pt)
          acc[mt][pt] = __builtin_amdgcn_mfma_f32_16x16x32_bf16(afr[mt], bfr[pt],
                                                                acc[mt][pt], 0, 0, 0);
    }
  }
  size_t sbase = (((size_t)b * NC + c) * NH + h) * (size_t)(HD * DS);
#pragma unroll
  for (int mt = 0; mt < 2; ++mt)
#pragma unroll
    for (int pt = 0; pt < 4; ++pt) {
      int p = pt * 16 + fr;
      int n0 = wv * 32 + mt * 16 + oct * 4;
      u32 lo = (u32)f2us(acc[mt][pt][0]) | ((u32)f2us(acc[mt][pt][1]) << 16);
      u32 hi = (u32)f2us(acc[mt][pt][2]) | ((u32)f2us(acc[mt][pt][3]) << 16);
      *(uint2*)&st16[sbase + (size_t)p * DS + n0] = make_uint2(lo, hi);
    }
}

// ---- inter-chunk scan (bf16 states, fp32 carry in registers) ----------------
__global__ __launch_bounds__(256) void scan_k(u16* __restrict__ st16,
                                              const float* __restrict__ Acs) {
  const int t = threadIdx.x;
  const int seg = blockIdx.x & 15;
  const int bh = blockIdx.x >> 4;
  const int h = bh & 31, b = bh >> 5;
  const int e2 = seg * 256 + t;             // u32-pair index within 8192-elem tile
  const size_t acssb = ((size_t)b * NH + h) * NC * CH;
  float run0 = 0.0f, run1 = 0.0f;
#pragma unroll
  for (int c = 0; c < NC; ++c) {
    float dAl = __expf(Acs[acssb + (size_t)c * CH + (CH - 1)]);
    size_t e = (((size_t)b * NC + c) * NH + h) * (size_t)(HD * DS) + e2 * 2;
    u32 v = *(const u32*)&st16[e];
    float s0 = us2f((u16)(v & 0xffffu)), s1 = us2f((u16)(v >> 16));
    *(u32*)&st16[e] = (u32)f2us(run0) | ((u32)f2us(run1) << 16);
    run0 = fmaf(dAl, run0, s0);
    run1 = fmaf(dAl, run1, s1);
  }
}

// ---- merged SSD: one 8-wave block per (b,c,h); C in regs; Yo folded ---------
// LDS pool (u16): B [64][128] @0 | Xt [64][72] @8192 | P 8x[32][72] @12800
// state staging [64][136] reuses @0 region before the st loop.
#define SP 72
#define XOFF 8192
#define POFF 12800
__global__ __launch_bounds__(512, 4) void ssd_out_k(const u16* __restrict__ xbc,
                                                    const float* __restrict__ dtp,
                                                    const float* __restrict__ Acs,
                                                    const u16* __restrict__ st16,
                                                    const float* __restrict__ Dvec,
                                                    u16* __restrict__ y) {
  __shared__ u16 pool[31232];
  __shared__ float acs_s[256];
  const int t = threadIdx.x;
  const int w = t >> 6, lane = t & 63;
  const int fr = lane & 15, oct = lane >> 4;
  const int h = blockIdx.x & 31, c = (blockIdx.x >> 5) & 15, b = blockIdx.x >> 9;
  const size_t acsb = (((size_t)b * NH + h) * NC + c) * CH;
  const size_t rowbase = (size_t)b * L_ + c * CH;
  if (t < 256) acs_s[t] = Acs[acsb + t];
  // stage init-state bf16 [64 p][136]
  const size_t sb = (((size_t)b * NC + c) * NH + h) * (size_t)(HD * DS);
#pragma unroll
  for (int i = 0; i < 2; ++i) {
    int ci = i * 512 + t; int p = ci >> 4, nk = ci & 15;
    uint4 v = *(const uint4*)&st16[sb + (size_t)p * DS + nk * 8];
    *(uint4*)&pool[p * 136 + nk * 8] = v;
  }
  __syncthreads();
  // C fragments in registers (raw row-major reads; same data the LDS held before)
  bf16x8 ca[2][4];
#pragma unroll
  for (int mt = 0; mt < 2; ++mt)
#pragma unroll
    for (int kk = 0; kk < 4; ++kk)
      ca[mt][kk] = *(const bf16x8*)&xbc[(rowbase + w * 32 + mt * 16 + fr) * CONVD +
                                        DI + DS + kk * 32 + oct * 8];
  f32x4 acc_y[2][4];
#pragma unroll
  for (int mt = 0; mt < 2; ++mt)
#pragma unroll
    for (int pp4 = 0; pp4 < 4; ++pp4) acc_y[mt][pp4] = (f32x4){0.f, 0.f, 0.f, 0.f};

  // Yo first: acc_y = (exp(AcsL)*C) . state^T   (A-row scaling == D-row scaling)
  {
    float eL0 = __expf(acs_s[w * 32 + fr]);
    float eL1 = __expf(acs_s[w * 32 + 16 + fr]);
#pragma unroll
    for (int kk = 0; kk < 4; ++kk) {
      bf16x8 c0 = scale8(ca[0][kk], eL0);
      bf16x8 c1 = scale8(ca[1][kk], eL1);
#pragma unroll
      for (int pp4 = 0; pp4 < 4; ++pp4) {
        bf16x8 sf = *(const bf16x8*)&pool[(pp4 * 16 + fr) * 136 + kk * 32 + oct * 8];
        acc_y[0][pp4] = __builtin_amdgcn_mfma_f32_16x16x32_bf16(c0, sf, acc_y[0][pp4], 0, 0, 0);
        acc_y[1][pp4] = __builtin_amdgcn_mfma_f32_16x16x32_bf16(c1, sf, acc_y[1][pp4], 0, 0, 0);
      }
    }
  }

  const int stmax = w >> 1, delta = (w & 1) << 5;
  for (int st = 0; st < 4; ++st) {
    __syncthreads();   // previous tile (or state) reads complete before overwrite
    // stage B[st] [64][128] swizzled
#pragma unroll
    for (int i = 0; i < 2; ++i) {
      int ci = i * 512 + t; int ll = ci >> 4, ck = ci & 15;
      uint4 v = *(const uint4*)&xbc[(rowbase + st * 64 + ll) * CONVD + DI + ck * 8];
      *(uint4*)&pool[ll * 128 + ((ck * 8) ^ ((ll & 7) << 3))] = v;
    }
    // stage Xt[p][s] = x[s][p]*dt[s], group-XOR swizzled (states_k pattern)
    {
      int s = t >> 3, pk = t & 7;
      size_t row = rowbase + st * 64 + s;
      uint4 v = *(const uint4*)&xbc[row * CONVD + h * HD + pk * 8];
      float d = dtp[row * NH + h];
      float o[8]; unpack8(v, o);
#pragma unroll
      for (int qq = 0; qq < 8; ++qq) {
        int r = pk * 8 + qq;
        pool[XOFF + r * SP + ((((s >> 3) ^ (r >> 3)) & 7) << 3) + (s & 7)] = f2us(o[qq] * d);
      }
    }
    __syncthreads();
    if (st > stmax) continue;  // wave-uniform; no barriers in skipped region
    const bool diag = (st == stmax);
    // scores -> P strip (wave-private)
#pragma unroll
    for (int ss4 = 0; ss4 < 4; ++ss4) {
      bf16x8 bbf[4];
#pragma unroll
      for (int kk = 0; kk < 4; ++kk)
        bbf[kk] = *(const bf16x8*)&pool[(ss4 * 16 + fr) * 128 +
                                        ((kk * 32 + oct * 8) ^ ((fr & 7) << 3))];
      int s_in = ss4 * 16 + fr;
      float aS = acs_s[st * 64 + s_in];
#pragma unroll
      for (int mt = 0; mt < 2; ++mt) {
        f32x4 sacc = (f32x4){0.f, 0.f, 0.f, 0.f};
#pragma unroll
        for (int kk = 0; kk < 4; ++kk)
          sacc = __builtin_amdgcn_mfma_f32_16x16x32_bf16(ca[mt][kk], bbf[kk], sacc, 0, 0, 0);
#pragma unroll
        for (int i = 0; i < 4; ++i) {
          int r = mt * 16 + oct * 4 + i;
          float aL = acs_s[w * 32 + r];
          float wgt = (!diag || (s_in <= r + delta)) ? __expf(aL - aS) : 0.0f;
          pool[POFF + w * 2304 + r * SP + s_in] = f2us(sacc[i] * wgt);
        }
      }
    }
    // PV: acc_y += P(32x64) . X(64x64)^T
    bf16x8 pa[2][2];
#pragma unroll
    for (int mt = 0; mt < 2; ++mt)
#pragma unroll
      for (int k2 = 0; k2 < 2; ++k2)
        pa[mt][k2] = *(const bf16x8*)&pool[POFF + w * 2304 + (mt * 16 + fr) * SP +
                                           k2 * 32 + oct * 8];
#pragma unroll
    for (int pp4 = 0; pp4 < 4; ++pp4) {
      int rx = pp4 * 16 + fr, xg = rx >> 3;
      bf16x8 xb0 = *(const bf16x8*)&pool[XOFF + rx * SP + (((oct) ^ xg) & 7) * 8];
      bf16x8 xb1 = *(const bf16x8*)&pool[XOFF + rx * SP + (((4 + oct) ^ xg) & 7) * 8];
#pragma unroll
      for (int mt = 0; mt < 2; ++mt) {
        acc_y[mt][pp4] = __builtin_amdgcn_mfma_f32_16x16x32_bf16(pa[mt][0], xb0, acc_y[mt][pp4], 0, 0, 0);
        acc_y[mt][pp4] = __builtin_amdgcn_mfma_f32_16x16x32_bf16(pa[mt][1], xb1, acc_y[mt][pp4], 0, 0, 0);
      }
    }
  }

  // write y = Yd + Yo + D*xs
  const float Dh = Dvec[h];
#pragma unroll
  for (int mt = 0; mt < 2; ++mt)
#pragma unroll
    for (int i = 0; i < 4; ++i) {
      size_t row = rowbase + w * 32 + mt * 16 + oct * 4 + i;
#pragma unroll
      for (int pp4 = 0; pp4 < 4; ++pp4) {
        int col = h * HD + pp4 * 16 + fr;
        float xs = us2f(xbc[row * CONVD + col]);
        y[row * DI + col] = f2us(acc_y[mt][pp4][i] + Dh * xs);
      }
    }
}

// ---- gated RMSNorm in place on y (bf16)
__global__ __launch_bounds__(256) void gnorm_k(const u16* __restrict__ zb,
                                               const float* __restrict__ nw,
                                               u16* __restrict__ y) {
  const int row = blockIdx.x, t = threadIdx.x;
  const u16* zr = zb + (size_t)row * DI;
  u16* yr = y + (size_t)row * DI;
  uint4 zv = *(const uint4*)&zr[t * 8];
  uint4 yv = *(const uint4*)&yr[t * 8];
  float uz[8], uy[8];
  unpack8(zv, uz); unpack8(yv, uy);
  float u[8], ssum = 0.0f;
#pragma unroll
  for (int j = 0; j < 8; ++j) { u[j] = uy[j] * silu_(uz[j]); ssum += u[j] * u[j]; }
#pragma unroll
  for (int off = 32; off >= 1; off >>= 1) ssum += __shfl_xor(ssum, off, 64);
  __shared__ float red[4];
  if ((t & 63) == 0) red[t >> 6] = ssum;
  __syncthreads();
  float sc = rsqrtf((red[0] + red[1] + red[2] + red[3]) * (1.0f / DI) + 1e-5f);
  float4 w0 = *(const float4*)&nw[t * 8];
  float4 w1 = *(const float4*)&nw[t * 8 + 4];
  float o0 = u[0] * sc * w0.x, o1 = u[1] * sc * w0.y, o2 = u[2] * sc * w0.z, o3 = u[3] * sc * w0.w;
  float o4 = u[4] * sc * w1.x, o5 = u[5] * sc * w1.y, o6 = u[6] * sc * w1.z, o7 = u[7] * sc * w1.w;
  uint4 ov;
  ov.x = (u32)f2us(o0) | ((u32)f2us(o1) << 16);
  ov.y = (u32)f2us(o2) | ((u32)f2us(o3) << 16);
  ov.z = (u32)f2us(o4) | ((u32)f2us(o5) << 16);
  ov.w = (u32)f2us(o6) | ((u32)f2us(o7) << 16);
  *(uint4*)&yr[t * 8] = ov;
}

extern "C" void kernel_launch(void* const* d_in, const int* in_sizes, int n_in,
                              void* d_out, int out_size, void* d_ws, size_t ws_size,
                              hipStream_t stream) {
  const float* x      = (const float*)d_in[0];
  const float* W_in   = (const float*)d_in[1];
  const float* conv_w = (const float*)d_in[2];
  const float* conv_b = (const float*)d_in[3];
  const float* dt_b   = (const float*)d_in[4];
  const float* A_log  = (const float*)d_in[5];
  const float* Dvec   = (const float*)d_in[6];
  const float* norm_w = (const float*)d_in[7];
  const float* W_out  = (const float*)d_in[8];
  float* out = (float*)d_out;

  // workspace layout (144.7 MB total)
  u16* zb       = (u16*)d_ws;                              // 33.55 MB
  u16* xbc      = zb + (size_t)B_ * L_ * DI;               // 37.75 MB
  float* dtp    = (float*)(xbc + (size_t)B_ * L_ * CONVD); // 1.05 MB
  float* Acs    = dtp + (size_t)B_ * L_ * NH;              // 1.05 MB
  u16* stregion = (u16*)(Acs + (size_t)B_ * NH * L_);      // 33.55 MB region
  u16* uni      = stregion + (size_t)B_ * NC * NH * HD * DS * 2;  // 37.75 MB
  u16* xraw = uni;  // dead after conv
  u16* y    = uni;  // aliases xraw

  // region timeline: [xb16 (16.8MB) | wint (8.9MB)] -> states16 (16.8MB) -> woutt
  u16* xb16     = stregion;                                   // until gemm_in done
  u16* wint     = stregion + (size_t)B_ * L_ * DM;            // until gemm_in done
  u16* states16 = stregion;                                   // states_k .. ssd_out_k
  u16* woutt    = stregion;                                   // after ssd_out_k

  const int Mrows = B_ * L_;

  dt_gemm_k<<<Mrows / 8, 256, 0, stream>>>(x, W_in, dt_b, dtp, xb16);
  cvt_t_k<<<dim3(NGEMM / 64, DM / 64), 256, 0, stream>>>(W_in, wint, DPROJ, DM);

  const int nwg_in = (Mrows / 128) * (NGEMM / 128);   // 2176
  gemm_bf16_k<DM, NGEMM / 128, 0><<<nwg_in, 256, 0, stream>>>(
      xb16, wint, zb, xraw, nullptr, nwg_in);

  conv_silu_k<<<(Mrows * (CONVD / 8)) / 256, 256, 0, stream>>>(xraw, conv_w, conv_b, xbc);
  acs_k<<<(B_ * NH * NC) / 4, 256, 0, stream>>>(dtp, A_log, Acs);
  states_k<<<B_ * NC * NH, 256, 0, stream>>>(xbc, dtp, Acs, states16);
  scan_k<<<B_ * NH * 16, 256, 0, stream>>>(states16, Acs);
  ssd_out_k<<<B_ * NC * NH, 512, 0, stream>>>(xbc, dtp, Acs, states16, Dvec, y);
  gnorm_k<<<Mrows, 256, 0, stream>>>(zb, norm_w, y);

  cvt_t_k<<<dim3(DM / 64, DI / 64), 256, 0, stream>>>(W_out, woutt, DM, DI);
  const int nwg_out = (Mrows / 128) * (DM / 128);     // 512
  gemm_bf16_k<DI, DM / 128, 1><<<nwg_out, 256, 0, stream>>>(
      y, woutt, nullptr, nullptr, out, nwg_out);
}